// Round 10
// baseline (501.597 us; speedup 1.0000x reference)
//
#include <hip/hip_runtime.h>
#include <hip/hip_bf16.h>
#include <cstdint>

static constexpr int N_  = 16384;
static constexpr int E_  = 131072;
static constexpr int D_  = 768;
static constexpr int D2_ = 1536;
static constexpr int DSQ_ = D_ * D_;

// ---------------- workspace layout (bytes), total ~219.3 MB ----------------
static constexpr size_t OFF_XB   = 0;            // N*D bf16    = 25165824
static constexpr size_t OFF_WCT  = 25165824;     // 12*D*D bf16 = 14155776
static constexpr size_t OFF_WLT  = 39321600;     // D*2D bf16   = 2359296
static constexpr size_t OFF_NB16 = 41680896;     // N*2D bf16   = 50331648
static constexpr size_t OFF_H4   = 92012544;     // 4 * N*D bf16 = 100663296
static constexpr size_t OFF_ZB   = 92012544;     // N*D fp32 (reuses H4 after gathers)
static constexpr size_t OFF_N1C  = 192675840;    // N*D bf16 carry = 25165824
static constexpr size_t OFF_TG   = 217841664;    // E int32     = 524288
static constexpr size_t OFF_PAY  = 218365952;    // E int32     = 524288
static constexpr size_t OFF_CNT  = 218890240;    // N*4 int32   = 262144
static constexpr size_t OFF_BASE = 219152384;    // (N+1) int32, padded to 65552
static constexpr size_t OFF_CUR  = 219217936;    // N int32     = 65536
static constexpr size_t OFF_BC   = 219283472;    // 512 int32
static constexpr size_t OFF_SCAN = 219285520;    // 513 int32

typedef __attribute__((ext_vector_type(8))) short short8v;
typedef __attribute__((ext_vector_type(4))) float floatx4;

__device__ __forceinline__ void gld16(const void* g, void* l) {
  __builtin_amdgcn_global_load_lds(
      (const __attribute__((address_space(1))) unsigned int*)g,
      (__attribute__((address_space(3))) unsigned int*)l, 16, 0, 0);
}

__device__ __forceinline__ float b2f(short u) {
  union { unsigned int i; float f; } x;
  x.i = ((unsigned int)(unsigned short)u) << 16;
  return x.f;
}

__device__ __forceinline__ float wave_sum(float v) {
#pragma unroll
  for (int o = 32; o; o >>= 1) v += __shfl_down(v, o, 64);
  return v;
}

// WcT[ft][h][d] = sum_b coeff_f[t,b] * W_f[b][d][h]  (bf16, transposed)
__global__ __launch_bounds__(256) void combine_wt_kernel(
    const float* __restrict__ Wt, const float* __restrict__ ct,
    const float* __restrict__ Wu, const float* __restrict__ cu,
    const float* __restrict__ Wd, const float* __restrict__ cd,
    __hip_bfloat16* __restrict__ WcT) {
  int i  = blockIdx.x * 256 + threadIdx.x;   // < D*D, i = d*768 + h
  int ft = blockIdx.y;                        // 0..11
  int f = ft >> 2, t = ft & 3;
  const float* W = (f == 0) ? Wt : ((f == 1) ? Wu : Wd);
  const float* c = ((f == 0) ? ct : ((f == 1) ? cu : cd)) + t * 3;
  float v = c[0] * W[i] + c[1] * W[DSQ_ + i] + c[2] * W[2 * DSQ_ + i];
  int d = i / D_, h = i % D_;
  WcT[(size_t)ft * DSQ_ + (size_t)h * D_ + d] = __float2bfloat16(v);
}

// W_linT[h][k] = W_lin[k][h] (bf16)
__global__ __launch_bounds__(256) void wlint_kernel(
    const float* __restrict__ W, __hip_bfloat16* __restrict__ WT) {
  int i = blockIdx.x * 256 + threadIdx.x;    // < 2D*D, i = k*768 + h
  int k = i / D_, h = i % D_;
  WT[(size_t)h * D2_ + k] = __float2bfloat16(W[i]);
}

__global__ __launch_bounds__(256) void ln_kernel(
    const float* __restrict__ h, const float* __restrict__ gamma,
    const float* __restrict__ beta, __hip_bfloat16* __restrict__ x) {
  int v = blockIdx.x, tid = threadIdx.x;
  const float* hr = h + (size_t)v * D_;
  float e0 = hr[tid], e1 = hr[tid + 256], e2 = hr[tid + 512];
  float s = e0 + e1 + e2;
  float q = e0 * e0 + e1 * e1 + e2 * e2;
  __shared__ float red[8];
  __shared__ float mv[2];
  float ws_ = wave_sum(s), wq = wave_sum(q);
  int lane = tid & 63, w = tid >> 6;
  if (lane == 0) { red[w] = ws_; red[4 + w] = wq; }
  __syncthreads();
  if (tid == 0) {
    float S = red[0] + red[1] + red[2] + red[3];
    float Q = red[4] + red[5] + red[6] + red[7];
    float mu = S * (1.0f / D_);
    float var = Q * (1.0f / D_) - mu * mu;
    mv[0] = mu;
    mv[1] = rsqrtf(var + 1e-5f);
  }
  __syncthreads();
  float mu = mv[0], rstd = mv[1];
  __hip_bfloat16* xr = x + (size_t)v * D_;
  xr[tid]       = __float2bfloat16((e0 - mu) * rstd * gamma[tid]       + beta[tid]);
  xr[tid + 256] = __float2bfloat16((e1 - mu) * rstd * gamma[tid + 256] + beta[tid + 256]);
  xr[tid + 512] = __float2bfloat16((e2 - mu) * rstd * gamma[tid + 512] + beta[tid + 512]);
}

// per-block hete counts + (dst,etype) histogram
__global__ __launch_bounds__(256) void edge_a_kernel(
    const int* __restrict__ hete, const int* __restrict__ dst,
    const int* __restrict__ etype, int* __restrict__ blockcnt,
    int* __restrict__ cnt4) {
  int j = blockIdx.x * 256 + threadIdx.x;
  int flag = hete[j] > 0;
  unsigned long long m = __ballot(flag);
  __shared__ int wsum[4];
  int lane = threadIdx.x & 63, w = threadIdx.x >> 6;
  if (lane == 0) wsum[w] = __popcll(m);
  __syncthreads();
  if (threadIdx.x == 0)
    blockcnt[blockIdx.x] = wsum[0] + wsum[1] + wsum[2] + wsum[3];
  atomicAdd(&cnt4[dst[j] * 4 + etype[j]], 1);
}

// single-block scan over 512 block counts -> exclusive offsets + total K
__global__ __launch_bounds__(512) void scan_kernel(
    const int* __restrict__ blockcnt, int* __restrict__ scanout) {
  __shared__ int s[512];
  int t = threadIdx.x;
  int v = blockcnt[t];
  s[t] = v;
  __syncthreads();
  for (int o = 1; o < 512; o <<= 1) {
    int add = (t >= o) ? s[t - o] : 0;
    __syncthreads();
    s[t] += add;
    __syncthreads();
  }
  scanout[t] = s[t] - v;             // exclusive prefix
  if (t == 511) scanout[512] = s[511];  // total hete count K
}

// target[j] = dst[perm_inv[j]]
__global__ __launch_bounds__(256) void edge_b_kernel(
    const int* __restrict__ hete, const int* __restrict__ dst,
    const int* __restrict__ scanout, int* __restrict__ target) {
  int j = blockIdx.x * 256 + threadIdx.x;
  int flag = hete[j] > 0;
  unsigned long long m = __ballot(flag);
  __shared__ int wsum[4];
  int lane = threadIdx.x & 63, w = threadIdx.x >> 6;
  if (lane == 0) wsum[w] = __popcll(m);
  __syncthreads();
  int wpre = 0;
#pragma unroll
  for (int i = 0; i < 4; i++) wpre += (i < w) ? wsum[i] : 0;
  int lpre = __popcll(m & ((1ull << lane) - 1ull));
  int hcum = scanout[blockIdx.x] + wpre + lpre;  // # hete edges with idx < j
  int K = scanout[512];
  int e = flag ? hcum : (K + j - hcum);
  target[j] = dst[e];
}

// base[v] = exclusive prefix of deg[v] = sum_t cnt4[v,t]; base[N]=E
__global__ __launch_bounds__(1024) void base_scan_kernel(
    const int* __restrict__ cnt4, int* __restrict__ base) {
  __shared__ int s[1024];
  int t = threadIdx.x;
  int loc[16];
  int sum = 0;
#pragma unroll
  for (int i = 0; i < 16; i++) {
    int v = t * 16 + i;
    int d = cnt4[v * 4] + cnt4[v * 4 + 1] + cnt4[v * 4 + 2] + cnt4[v * 4 + 3];
    loc[i] = sum;
    sum += d;
  }
  s[t] = sum;
  __syncthreads();
  for (int o = 1; o < 1024; o <<= 1) {
    int add = (t >= o) ? s[t - o] : 0;
    __syncthreads();
    s[t] += add;
    __syncthreads();
  }
  int pre = t ? s[t - 1] : 0;
#pragma unroll
  for (int i = 0; i < 16; i++) base[t * 16 + i] = pre + loc[i];
  if (t == 1023) base[N_] = s[1023];
}

// payload[base[target[j]] + cursor++] = g<<14 | src[j]
__global__ __launch_bounds__(256) void edge_sort_kernel(
    const int* __restrict__ target, const int* __restrict__ src,
    const int* __restrict__ etype, const int* __restrict__ hete,
    const int* __restrict__ base, int* __restrict__ cursor,
    int* __restrict__ payload) {
  int j = blockIdx.x * 256 + threadIdx.x;
  int v = target[j];
  int p = base[v] + atomicAdd(&cursor[v], 1);
  int g = ((hete[j] > 0) ? 0 : 4) + etype[j];
  payload[p] = (g << 14) | src[j];
}

// one wave per node; groups [g0, g0+4). Lane owns elems [lane*8,+8) and
// [512+lane*4,+4) -> 16B + 8B vector loads per edge row (G13).
template <bool FIRST>
__global__ __launch_bounds__(256) void gather_n1_kernel(
    const __hip_bfloat16* __restrict__ H, const int* __restrict__ base,
    const int* __restrict__ payload, __hip_bfloat16* __restrict__ n1c,
    __hip_bfloat16* __restrict__ nb16, int g0) {
  int wv = threadIdx.x >> 6, lane = threadIdx.x & 63;
  int v = blockIdx.x * 4 + wv;
  int b0 = base[v], b1 = base[v + 1];
  float acc[12];
  if (FIRST) {
#pragma unroll
    for (int i = 0; i < 12; i++) acc[i] = 0.f;
  } else {
    short8v a8 = *(const short8v*)(n1c + (size_t)v * D_ + lane * 8);
    short4  b4 = *(const short4*)(n1c + (size_t)v * D_ + 512 + lane * 4);
#pragma unroll
    for (int i = 0; i < 8; i++) acc[i] = b2f(a8[i]);
    acc[8] = b2f(b4.x); acc[9] = b2f(b4.y);
    acc[10] = b2f(b4.z); acc[11] = b2f(b4.w);
  }
  for (int idx = b0; idx < b1; ++idx) {
    int pl = payload[idx];
    int g = (pl >> 14) - g0;
    if ((unsigned)g > 3u) continue;
    const __hip_bfloat16* row = H + ((size_t)g * N_ + (pl & 16383)) * D_;
    short8v a8 = *(const short8v*)(row + lane * 8);
    short4  b4 = *(const short4*)(row + 512 + lane * 4);
#pragma unroll
    for (int i = 0; i < 8; i++) acc[i] += b2f(a8[i]);
    acc[8] += b2f(b4.x); acc[9] += b2f(b4.y);
    acc[10] += b2f(b4.z); acc[11] += b2f(b4.w);
  }
  __hip_bfloat16 o[12];
#pragma unroll
  for (int i = 0; i < 12; i++) o[i] = __float2bfloat16(acc[i]);
  if (FIRST) {
    *(short8v*)(n1c + (size_t)v * D_ + lane * 8) = *(const short8v*)o;
    *(short4*)(n1c + (size_t)v * D_ + 512 + lane * 4) = *(const short4*)(o + 8);
  } else {
    *(short8v*)(nb16 + (size_t)v * D2_ + lane * 8) = *(const short8v*)o;
    *(short4*)(nb16 + (size_t)v * D2_ + 512 + lane * 4) = *(const short4*)(o + 8);
  }
}

// nb16[v][768+k] = sum_t cnt4[v,t] * H4[t][v][k]; thread per 8 elems
__global__ __launch_bounds__(256) void combine_n2_kernel(
    const __hip_bfloat16* __restrict__ H4, const int* __restrict__ cnt4,
    __hip_bfloat16* __restrict__ nb16) {
  size_t i = ((size_t)blockIdx.x * 256 + threadIdx.x) * 8;  // < N*D
  int v = (int)(i / D_);
  int k = (int)(i % D_);
  float acc[8] = {0.f, 0.f, 0.f, 0.f, 0.f, 0.f, 0.f, 0.f};
#pragma unroll
  for (int t = 0; t < 4; t++) {
    float c = (float)cnt4[v * 4 + t];
    if (c != 0.f) {
      short8v hv = *(const short8v*)(H4 + (size_t)t * N_ * D_ + i);
#pragma unroll
      for (int j = 0; j < 8; j++) acc[j] += c * b2f(hv[j]);
    }
  }
  __hip_bfloat16 o[8];
#pragma unroll
  for (int j = 0; j < 8; j++) o[j] = __float2bfloat16(acc[j]);
  *(short8v*)(nb16 + (size_t)v * D2_ + D_ + k) = *(const short8v*)o;
}

// ---- 8-phase 256x256 GEMM, 9-unit LDS ring, depth-6 prefetch ----
// K-half unit = [256 rows][32 K] bf16 = 16 KB, stored as 128 lines x 128B:
// logical (r, p) (p = 16B k-slot 0..3) -> line u = r>>1, slot s = (r&1)*4+p,
// physical slot s ^ (u&7). Bijective; frag reads are 2-way banked = free.
__device__ __forceinline__ int fragaddr(int r, int p) {
  int u = r >> 1;
  int s = ((r & 1) << 2) | p;
  return u * 128 + ((s ^ (u & 7)) << 4);
}

// stage one K-half unit (2 x gld16 per thread, 512 threads)
__device__ __forceinline__ void stage_kh(const __hip_bfloat16* X, int K,
                                         int rowbase, int kglob, char* unit,
                                         int tid) {
#pragma unroll
  for (int j = 0; j < 2; j++) {
    int q = j * 512 + tid;        // 16B slot 0..1023
    int u = q >> 3;               // 128B line
    int sp = q & 7;               // physical slot
    int s = sp ^ (u & 7);         // logical slot
    int r = (u << 1) | (s >> 2);
    int p = s & 3;
    gld16(X + (size_t)(rowbase + r) * K + kglob + p * 8, unit + q * 16);
  }
}

__device__ __forceinline__ int wrap9(int x) { return x >= 9 ? x - 9 : x; }

// C[z][M,N] = relu(A[M,K] @ BT[z][N,K]^T (+bias)). BM=BN=256, BK=64,
// 512 thr = 8 waves (2M x 4N), per-wave 128x64 out.
// LDS: ring of 9 x 16KB K-half units (144 KB). Unit uid: A0(t)=4t, B0=4t+1,
// A1=4t+2, B1=4t+3; slot = uid % 9; staged at phase uid-6 (depth 6 phases):
// phase (t,j): j0 stages A1(t+1), j1 B1(t+1), j2 A0(t+2), j3 B0(t+2).
// Per-thread load ledger (2 loads/unit) gives uniform vmcnt(8) at each phase
// end in steady state; tail: (nt-2,j3)->4, (nt-1,j0)->4, (nt-1,j1)->0.
// Slot reuse is >=3 barrier-locked phases after last read (audited).
template <bool BIAS, bool OUTBF16>
__global__ __launch_bounds__(512, 1) void gemm8p_kernel(
    const __hip_bfloat16* __restrict__ A, const __hip_bfloat16* __restrict__ BT0,
    const float* __restrict__ bias, void* __restrict__ Cv,
    int M, int N, int K, size_t strideB, size_t strideC) {
  __shared__ char lds[147456];
  const int tid = threadIdx.x, lane = tid & 63, wv = tid >> 6;
  const int wr = wv >> 2, wcn = wv & 3;
  // XCD swizzle over (bx, z, by): each XCD owns a contiguous by-chunk.
  int gx = gridDim.x, gz = gridDim.z;
  int nwg = gx * gridDim.y * gz;
  int id = (blockIdx.z * gridDim.y + blockIdx.y) * gx + blockIdx.x;
  int s = (id & 7) * (nwg >> 3) + (id >> 3);
  int bx = s % gx;
  int rem = s / gx;
  int z = rem % gz;
  int by = rem / gz;
  const __hip_bfloat16* BT = BT0 + (size_t)z * strideB;
  int row0 = by * 256, col0 = bx * 256;
  const int nt = K >> 6;

  floatx4 acc[8][4];
#pragma unroll
  for (int i = 0; i < 8; i++)
#pragma unroll
    for (int j = 0; j < 4; j++) acc[i][j] = floatx4{0.f, 0.f, 0.f, 0.f};

  // prologue: stage uids 0..5 into slots 0..5
  stage_kh(A, K, row0, 0, lds, tid);                    // A0(0)
  stage_kh(BT, K, col0, 0, lds + 16384, tid);           // B0(0)
  stage_kh(A, K, row0, 32, lds + 2 * 16384, tid);       // A1(0)
  stage_kh(BT, K, col0, 32, lds + 3 * 16384, tid);      // B1(0)
  stage_kh(A, K, row0, 64, lds + 4 * 16384, tid);       // A0(1)
  stage_kh(BT, K, col0, 64, lds + 5 * 16384, tid);      // B0(1)
  asm volatile("s_waitcnt vmcnt(8)" ::: "memory");      // uids 0,1 landed
  __builtin_amdgcn_s_barrier();
  asm volatile("" ::: "memory");

  int su = 0;  // slot of A0(t)
  for (int t = 0; t < nt; ++t) {
    char* A0u = lds + su * 16384;
    char* B0u = lds + wrap9(su + 1) * 16384;
    char* A1u = lds + wrap9(su + 2) * 16384;
    char* B1u = lds + wrap9(su + 3) * 16384;
    char* st6 = lds + wrap9(su + 6) * 16384;   // A1(t+1)
    char* st7 = lds + wrap9(su + 7) * 16384;   // B1(t+1)
    char* st8 = lds + wrap9(su + 8) * 16384;   // A0(t+2)
    char* st9 = lds + su * 16384;              // B0(t+2) (uid+9 -> same slot)
    short8v af[8];
#pragma unroll
    for (int j = 0; j < 4; ++j) {
      const int ks = j >> 1, ch = j & 1;
      char* Au = (ks == 0) ? A0u : A1u;
      char* Bu = (ks == 0) ? B0u : B1u;
      if (ch == 0) {
#pragma unroll
        for (int rf = 0; rf < 8; ++rf) {
          int r = wr * 128 + rf * 16 + (lane & 15);
          af[rf] = *(const short8v*)(Au + fragaddr(r, lane >> 4));
        }
      }
      short8v bfr[2];
#pragma unroll
      for (int nf = 0; nf < 2; ++nf) {
        int r = wcn * 64 + ch * 32 + nf * 16 + (lane & 15);
        bfr[nf] = *(const short8v*)(Bu + fragaddr(r, lane >> 4));
      }
      // staging (1 unit/phase, depth 6)
      if (j == 0 && t + 1 < nt)
        stage_kh(A, K, row0, (t + 1) * 64 + 32, st6, tid);
      if (j == 1 && t + 1 < nt)
        stage_kh(BT, K, col0, (t + 1) * 64 + 32, st7, tid);
      if (j == 2 && t + 2 < nt)
        stage_kh(A, K, row0, (t + 2) * 64, st8, tid);
      if (j == 3 && t + 2 < nt)
        stage_kh(BT, K, col0, (t + 2) * 64, st9, tid);
      asm volatile("" ::: "memory");
      __builtin_amdgcn_s_barrier();
      asm volatile("" ::: "memory");
      __builtin_amdgcn_s_setprio(1);
#pragma unroll
      for (int rf = 0; rf < 8; ++rf)
#pragma unroll
        for (int nf = 0; nf < 2; ++nf)
          acc[rf][ch * 2 + nf] = __builtin_amdgcn_mfma_f32_16x16x32_bf16(
              af[rf], bfr[nf], acc[rf][ch * 2 + nf], 0, 0, 0);
      __builtin_amdgcn_s_setprio(0);
      // derived waits (per-thread ledger; see header comment)
      if (j == 0) {
        if (t < nt - 1) asm volatile("s_waitcnt vmcnt(8)" ::: "memory");
        else            asm volatile("s_waitcnt vmcnt(4)" ::: "memory");
      } else if (j == 1) {
        if (t < nt - 1) asm volatile("s_waitcnt vmcnt(8)" ::: "memory");
        else            asm volatile("s_waitcnt vmcnt(0)" ::: "memory");
      } else if (j == 2) {
        if (t < nt - 1) asm volatile("s_waitcnt vmcnt(8)" ::: "memory");
      } else {
        if (t < nt - 2)      asm volatile("s_waitcnt vmcnt(8)" ::: "memory");
        else if (t == nt - 2) asm volatile("s_waitcnt vmcnt(4)" ::: "memory");
      }
      asm volatile("" ::: "memory");
      __builtin_amdgcn_s_barrier();
      asm volatile("" ::: "memory");
    }
    su = wrap9(su + 4);
  }
  // epilogue: C/D layout col=lane&15, row=(lane>>4)*4+q
#pragma unroll
  for (int rf = 0; rf < 8; ++rf) {
#pragma unroll
    for (int j = 0; j < 4; ++j) {
      int col = col0 + wcn * 64 + (j >> 1) * 32 + (j & 1) * 16 + (lane & 15);
      float bv = BIAS ? bias[col] : 0.f;
#pragma unroll
      for (int q = 0; q < 4; ++q) {
        int row = row0 + wr * 128 + rf * 16 + (lane >> 4) * 4 + q;
        float v = fmaxf(acc[rf][j][q] + bv, 0.f);
        if constexpr (OUTBF16) {
          ((__hip_bfloat16*)Cv + (size_t)z * strideC)[(size_t)row * N + col] =
              __float2bfloat16(v);
        } else {
          ((float*)Cv + (size_t)z * strideC)[(size_t)row * N + col] = v;
        }
      }
    }
  }
}

__global__ __launch_bounds__(256) void norm_kernel(
    const float* __restrict__ z, float* __restrict__ out) {
  int v = blockIdx.x, tid = threadIdx.x;
  const float* zr = z + (size_t)v * D_;
  float e0 = zr[tid], e1 = zr[tid + 256], e2 = zr[tid + 512];
  float q = e0 * e0 + e1 * e1 + e2 * e2;
  __shared__ float red[4];
  __shared__ float sc;
  float wq = wave_sum(q);
  int lane = tid & 63, w = tid >> 6;
  if (lane == 0) red[w] = wq;
  __syncthreads();
  if (tid == 0) {
    float S = red[0] + red[1] + red[2] + red[3];
    float norm = sqrtf(S);
    sc = (norm == 0.f) ? 1.f : (1.f / norm);
  }
  __syncthreads();
  float s = sc;
  float* orow = out + (size_t)v * D_;
  orow[tid]       = e0 * s;
  orow[tid + 256] = e1 * s;
  orow[tid + 512] = e2 * s;
}

extern "C" void kernel_launch(void* const* d_in, const int* in_sizes, int n_in,
                              void* d_out, int out_size, void* d_ws,
                              size_t ws_size, hipStream_t stream) {
  (void)in_sizes; (void)n_in; (void)out_size; (void)ws_size;
  const float* h      = (const float*)d_in[0];
  const float* W_text = (const float*)d_in[1];
  const float* c_text = (const float*)d_in[2];
  const float* W_user = (const float*)d_in[3];
  const float* c_user = (const float*)d_in[4];
  const float* W_dst  = (const float*)d_in[5];
  const float* c_dst  = (const float*)d_in[6];
  const float* gamma  = (const float*)d_in[7];
  const float* beta   = (const float*)d_in[8];
  const float* W_lin  = (const float*)d_in[9];
  const float* b_lin  = (const float*)d_in[10];
  const int* src      = (const int*)d_in[11];
  const int* dst      = (const int*)d_in[12];
  const int* etype    = (const int*)d_in[13];
  const int* hete     = (const int*)d_in[14];
  float* out          = (float*)d_out;

  char* ws = (char*)d_ws;
  __hip_bfloat16* xb   = (__hip_bfloat16*)(ws + OFF_XB);
  __hip_bfloat16* WcT  = (__hip_bfloat16*)(ws + OFF_WCT);
  __hip_bfloat16* WlT  = (__hip_bfloat16*)(ws + OFF_WLT);
  __hip_bfloat16* nb16 = (__hip_bfloat16*)(ws + OFF_NB16);
  __hip_bfloat16* H4   = (__hip_bfloat16*)(ws + OFF_H4);
  float* zbuf          = (float*)(ws + OFF_ZB);
  __hip_bfloat16* n1c  = (__hip_bfloat16*)(ws + OFF_N1C);
  int* target   = (int*)(ws + OFF_TG);
  int* payload  = (int*)(ws + OFF_PAY);
  int* cnt4     = (int*)(ws + OFF_CNT);
  int* base     = (int*)(ws + OFF_BASE);
  int* cursor   = (int*)(ws + OFF_CUR);
  int* blockcnt = (int*)(ws + OFF_BC);
  int* scanout  = (int*)(ws + OFF_SCAN);

  hipMemsetAsync(cnt4, 0, (size_t)N_ * 4 * 4, stream);
  hipMemsetAsync(cursor, 0, (size_t)N_ * 4, stream);

  combine_wt_kernel<<<dim3(DSQ_ / 256, 12), 256, 0, stream>>>(
      W_text, c_text, W_user, c_user, W_dst, c_dst, WcT);
  wlint_kernel<<<(D2_ * D_) / 256, 256, 0, stream>>>(W_lin, WlT);
  ln_kernel<<<N_, 256, 0, stream>>>(h, gamma, beta, xb);
  edge_a_kernel<<<E_ / 256, 256, 0, stream>>>(hete, dst, etype, blockcnt, cnt4);
  scan_kernel<<<1, 512, 0, stream>>>(blockcnt, scanout);
  edge_b_kernel<<<E_ / 256, 256, 0, stream>>>(hete, dst, scanout, target);
  base_scan_kernel<<<1, 1024, 0, stream>>>(cnt4, base);
  edge_sort_kernel<<<E_ / 256, 256, 0, stream>>>(target, src, etype, hete,
                                                 base, cursor, payload);

  const size_t HSTRIDE = (size_t)N_ * D_;
  const dim3 ggrid(D_ / 256, N_ / 256, 4);

  // dst family: 4 GEMMs batched (z) -> H4, then weighted combine into nb16
  gemm8p_kernel<false, true><<<ggrid, 512, 0, stream>>>(
      xb, WcT + (size_t)8 * DSQ_, nullptr, H4, N_, D_, D_, DSQ_, HSTRIDE);
  combine_n2_kernel<<<(N_ * D_) / (256 * 8), 256, 0, stream>>>(H4, cnt4, nb16);

  // src families: 2 passes of 4 groups each
  gemm8p_kernel<false, true><<<ggrid, 512, 0, stream>>>(
      xb, WcT, nullptr, H4, N_, D_, D_, DSQ_, HSTRIDE);
  gather_n1_kernel<true><<<N_ / 4, 256, 0, stream>>>(H4, base, payload, n1c,
                                                     nb16, 0);
  gemm8p_kernel<false, true><<<ggrid, 512, 0, stream>>>(
      xb, WcT + (size_t)4 * DSQ_, nullptr, H4, N_, D_, D_, DSQ_, HSTRIDE);
  gather_n1_kernel<false><<<N_ / 4, 256, 0, stream>>>(H4, base, payload, n1c,
                                                      nb16, 4);

  // z = relu(nb16 @ W_lin + b_lin) -> zbuf (reuses H4), then norm
  gemm8p_kernel<true, false><<<dim3(D_ / 256, N_ / 256, 1), 512, 0, stream>>>(
      nb16, WlT, b_lin, zbuf, N_, D_, D2_, 0, 0);
  norm_kernel<<<N_, 256, 0, stream>>>(zbuf, out);
}

// Round 11
// 492.314 us; speedup vs baseline: 1.0189x; 1.0189x over previous
//
#include <hip/hip_runtime.h>
#include <hip/hip_bf16.h>
#include <cstdint>

static constexpr int N_  = 16384;
static constexpr int E_  = 131072;
static constexpr int D_  = 768;
static constexpr int D2_ = 1536;
static constexpr int DSQ_ = D_ * D_;

// ---------------- workspace layout (bytes), total ~219.3 MB ----------------
static constexpr size_t OFF_XB   = 0;            // N*D bf16    = 25165824
static constexpr size_t OFF_WCT  = 25165824;     // 12*D*D bf16 = 14155776
static constexpr size_t OFF_WLT  = 39321600;     // D*2D bf16   = 2359296
static constexpr size_t OFF_NB16 = 41680896;     // N*2D bf16   = 50331648
static constexpr size_t OFF_H4   = 92012544;     // 4 * N*D bf16 = 100663296
static constexpr size_t OFF_ZB   = 92012544;     // N*D bf16 (reuses H4 after gathers)
static constexpr size_t OFF_N1C  = 192675840;    // N*D bf16 carry = 25165824
static constexpr size_t OFF_TG   = 217841664;    // E int32     = 524288
static constexpr size_t OFF_PAY  = 218365952;    // E int32     = 524288
static constexpr size_t OFF_CNT  = 218890240;    // N*4 int32   = 262144
static constexpr size_t OFF_BASE = 219152384;    // (N+1) int32, padded to 65552
static constexpr size_t OFF_CUR  = 219217936;    // N int32     = 65536
static constexpr size_t OFF_BC   = 219283472;    // 512 int32
static constexpr size_t OFF_SCAN = 219285520;    // 513 int32

typedef __attribute__((ext_vector_type(8))) short short8v;
typedef __attribute__((ext_vector_type(4))) float floatx4;

__device__ __forceinline__ void gld16(const void* g, void* l) {
  __builtin_amdgcn_global_load_lds(
      (const __attribute__((address_space(1))) unsigned int*)g,
      (__attribute__((address_space(3))) unsigned int*)l, 16, 0, 0);
}

__device__ __forceinline__ float b2f(short u) {
  union { unsigned int i; float f; } x;
  x.i = ((unsigned int)(unsigned short)u) << 16;
  return x.f;
}

__device__ __forceinline__ float wave_sum(float v) {
#pragma unroll
  for (int o = 32; o; o >>= 1) v += __shfl_down(v, o, 64);
  return v;
}

// WcT[ft][h][d] = sum_b coeff_f[t,b] * W_f[b][d][h]  (bf16), via LDS 64x64
// transpose so both global reads AND writes are coalesced (old version did
// 2B scattered writes -> partial-line RMW).
__global__ __launch_bounds__(256) void combine_wt_kernel(
    const float* __restrict__ Wt, const float* __restrict__ ct,
    const float* __restrict__ Wu, const float* __restrict__ cu,
    const float* __restrict__ Wd, const float* __restrict__ cd,
    __hip_bfloat16* __restrict__ WcT) {
  __shared__ float tile[64][65];
  int ft = blockIdx.y;                        // 0..11
  int f = ft >> 2, t = ft & 3;
  const float* W = (f == 0) ? Wt : ((f == 1) ? Wu : Wd);
  const float* c = ((f == 0) ? ct : ((f == 1) ? cu : cd)) + t * 3;
  int dt = (blockIdx.x / 12) * 64;            // d-tile base
  int ht = (blockIdx.x % 12) * 64;            // h-tile base
  int tid = threadIdx.x;
#pragma unroll
  for (int jj = 0; jj < 16; jj++) {
    int idx = jj * 256 + tid;
    int rr = idx >> 6, cc = idx & 63;         // (d-off, h-off)
    size_t i = (size_t)(dt + rr) * D_ + ht + cc;
    tile[rr][cc] = c[0] * W[i] + c[1] * W[DSQ_ + i] + c[2] * W[2 * DSQ_ + i];
  }
  __syncthreads();
#pragma unroll
  for (int jj = 0; jj < 16; jj++) {
    int idx = jj * 256 + tid;
    int hh = idx >> 6, dd = idx & 63;
    WcT[(size_t)ft * DSQ_ + (size_t)(ht + hh) * D_ + dt + dd] =
        __float2bfloat16(tile[dd][hh]);
  }
}

// W_linT[h][k] = W_lin[k][h] (bf16)
__global__ __launch_bounds__(256) void wlint_kernel(
    const float* __restrict__ W, __hip_bfloat16* __restrict__ WT) {
  int i = blockIdx.x * 256 + threadIdx.x;    // < 2D*D, i = k*768 + h
  int k = i / D_, h = i % D_;
  WT[(size_t)h * D2_ + k] = __float2bfloat16(W[i]);
}

__global__ __launch_bounds__(256) void ln_kernel(
    const float* __restrict__ h, const float* __restrict__ gamma,
    const float* __restrict__ beta, __hip_bfloat16* __restrict__ x) {
  int v = blockIdx.x, tid = threadIdx.x;
  const float* hr = h + (size_t)v * D_;
  float e0 = hr[tid], e1 = hr[tid + 256], e2 = hr[tid + 512];
  float s = e0 + e1 + e2;
  float q = e0 * e0 + e1 * e1 + e2 * e2;
  __shared__ float red[8];
  __shared__ float mv[2];
  float ws_ = wave_sum(s), wq = wave_sum(q);
  int lane = tid & 63, w = tid >> 6;
  if (lane == 0) { red[w] = ws_; red[4 + w] = wq; }
  __syncthreads();
  if (tid == 0) {
    float S = red[0] + red[1] + red[2] + red[3];
    float Q = red[4] + red[5] + red[6] + red[7];
    float mu = S * (1.0f / D_);
    float var = Q * (1.0f / D_) - mu * mu;
    mv[0] = mu;
    mv[1] = rsqrtf(var + 1e-5f);
  }
  __syncthreads();
  float mu = mv[0], rstd = mv[1];
  __hip_bfloat16* xr = x + (size_t)v * D_;
  xr[tid]       = __float2bfloat16((e0 - mu) * rstd * gamma[tid]       + beta[tid]);
  xr[tid + 256] = __float2bfloat16((e1 - mu) * rstd * gamma[tid + 256] + beta[tid + 256]);
  xr[tid + 512] = __float2bfloat16((e2 - mu) * rstd * gamma[tid + 512] + beta[tid + 512]);
}

// per-block hete counts + (dst,etype) histogram
__global__ __launch_bounds__(256) void edge_a_kernel(
    const int* __restrict__ hete, const int* __restrict__ dst,
    const int* __restrict__ etype, int* __restrict__ blockcnt,
    int* __restrict__ cnt4) {
  int j = blockIdx.x * 256 + threadIdx.x;
  int flag = hete[j] > 0;
  unsigned long long m = __ballot(flag);
  __shared__ int wsum[4];
  int lane = threadIdx.x & 63, w = threadIdx.x >> 6;
  if (lane == 0) wsum[w] = __popcll(m);
  __syncthreads();
  if (threadIdx.x == 0)
    blockcnt[blockIdx.x] = wsum[0] + wsum[1] + wsum[2] + wsum[3];
  atomicAdd(&cnt4[dst[j] * 4 + etype[j]], 1);
}

// single-block scan over 512 block counts -> exclusive offsets + total K
__global__ __launch_bounds__(512) void scan_kernel(
    const int* __restrict__ blockcnt, int* __restrict__ scanout) {
  __shared__ int s[512];
  int t = threadIdx.x;
  int v = blockcnt[t];
  s[t] = v;
  __syncthreads();
  for (int o = 1; o < 512; o <<= 1) {
    int add = (t >= o) ? s[t - o] : 0;
    __syncthreads();
    s[t] += add;
    __syncthreads();
  }
  scanout[t] = s[t] - v;             // exclusive prefix
  if (t == 511) scanout[512] = s[511];  // total hete count K
}

// target[j] = dst[perm_inv[j]]
__global__ __launch_bounds__(256) void edge_b_kernel(
    const int* __restrict__ hete, const int* __restrict__ dst,
    const int* __restrict__ scanout, int* __restrict__ target) {
  int j = blockIdx.x * 256 + threadIdx.x;
  int flag = hete[j] > 0;
  unsigned long long m = __ballot(flag);
  __shared__ int wsum[4];
  int lane = threadIdx.x & 63, w = threadIdx.x >> 6;
  if (lane == 0) wsum[w] = __popcll(m);
  __syncthreads();
  int wpre = 0;
#pragma unroll
  for (int i = 0; i < 4; i++) wpre += (i < w) ? wsum[i] : 0;
  int lpre = __popcll(m & ((1ull << lane) - 1ull));
  int hcum = scanout[blockIdx.x] + wpre + lpre;  // # hete edges with idx < j
  int K = scanout[512];
  int e = flag ? hcum : (K + j - hcum);
  target[j] = dst[e];
}

// base[v] = exclusive prefix of deg[v] = sum_t cnt4[v,t]; base[N]=E
__global__ __launch_bounds__(1024) void base_scan_kernel(
    const int* __restrict__ cnt4, int* __restrict__ base) {
  __shared__ int s[1024];
  int t = threadIdx.x;
  int loc[16];
  int sum = 0;
#pragma unroll
  for (int i = 0; i < 16; i++) {
    int v = t * 16 + i;
    int d = cnt4[v * 4] + cnt4[v * 4 + 1] + cnt4[v * 4 + 2] + cnt4[v * 4 + 3];
    loc[i] = sum;
    sum += d;
  }
  s[t] = sum;
  __syncthreads();
  for (int o = 1; o < 1024; o <<= 1) {
    int add = (t >= o) ? s[t - o] : 0;
    __syncthreads();
    s[t] += add;
    __syncthreads();
  }
  int pre = t ? s[t - 1] : 0;
#pragma unroll
  for (int i = 0; i < 16; i++) base[t * 16 + i] = pre + loc[i];
  if (t == 1023) base[N_] = s[1023];
}

// payload[base[target[j]] + cursor++] = g<<14 | src[j]
__global__ __launch_bounds__(256) void edge_sort_kernel(
    const int* __restrict__ target, const int* __restrict__ src,
    const int* __restrict__ etype, const int* __restrict__ hete,
    const int* __restrict__ base, int* __restrict__ cursor,
    int* __restrict__ payload) {
  int j = blockIdx.x * 256 + threadIdx.x;
  int v = target[j];
  int p = base[v] + atomicAdd(&cursor[v], 1);
  int g = ((hete[j] > 0) ? 0 : 4) + etype[j];
  payload[p] = (g << 14) | src[j];
}

// one wave per node; groups [g0, g0+4). Lane owns elems [lane*8,+8) and
// [512+lane*4,+4) -> 16B + 8B vector loads per edge row (G13).
template <bool FIRST>
__global__ __launch_bounds__(256) void gather_n1_kernel(
    const __hip_bfloat16* __restrict__ H, const int* __restrict__ base,
    const int* __restrict__ payload, __hip_bfloat16* __restrict__ n1c,
    __hip_bfloat16* __restrict__ nb16, int g0) {
  int wv = threadIdx.x >> 6, lane = threadIdx.x & 63;
  int v = blockIdx.x * 4 + wv;
  int b0 = base[v], b1 = base[v + 1];
  float acc[12];
  if (FIRST) {
#pragma unroll
    for (int i = 0; i < 12; i++) acc[i] = 0.f;
  } else {
    short8v a8 = *(const short8v*)(n1c + (size_t)v * D_ + lane * 8);
    short4  b4 = *(const short4*)(n1c + (size_t)v * D_ + 512 + lane * 4);
#pragma unroll
    for (int i = 0; i < 8; i++) acc[i] = b2f(a8[i]);
    acc[8] = b2f(b4.x); acc[9] = b2f(b4.y);
    acc[10] = b2f(b4.z); acc[11] = b2f(b4.w);
  }
  for (int idx = b0; idx < b1; ++idx) {
    int pl = payload[idx];
    int g = (pl >> 14) - g0;
    if ((unsigned)g > 3u) continue;
    const __hip_bfloat16* row = H + ((size_t)g * N_ + (pl & 16383)) * D_;
    short8v a8 = *(const short8v*)(row + lane * 8);
    short4  b4 = *(const short4*)(row + 512 + lane * 4);
#pragma unroll
    for (int i = 0; i < 8; i++) acc[i] += b2f(a8[i]);
    acc[8] += b2f(b4.x); acc[9] += b2f(b4.y);
    acc[10] += b2f(b4.z); acc[11] += b2f(b4.w);
  }
  __hip_bfloat16 o[12];
#pragma unroll
  for (int i = 0; i < 12; i++) o[i] = __float2bfloat16(acc[i]);
  if (FIRST) {
    *(short8v*)(n1c + (size_t)v * D_ + lane * 8) = *(const short8v*)o;
    *(short4*)(n1c + (size_t)v * D_ + 512 + lane * 4) = *(const short4*)(o + 8);
  } else {
    *(short8v*)(nb16 + (size_t)v * D2_ + lane * 8) = *(const short8v*)o;
    *(short4*)(nb16 + (size_t)v * D2_ + 512 + lane * 4) = *(const short4*)(o + 8);
  }
}

// nb16[v][768+k] = sum_t cnt4[v,t] * H4[t][v][k]; thread per 8 elems
__global__ __launch_bounds__(256) void combine_n2_kernel(
    const __hip_bfloat16* __restrict__ H4, const int* __restrict__ cnt4,
    __hip_bfloat16* __restrict__ nb16) {
  size_t i = ((size_t)blockIdx.x * 256 + threadIdx.x) * 8;  // < N*D
  int v = (int)(i / D_);
  int k = (int)(i % D_);
  float acc[8] = {0.f, 0.f, 0.f, 0.f, 0.f, 0.f, 0.f, 0.f};
#pragma unroll
  for (int t = 0; t < 4; t++) {
    float c = (float)cnt4[v * 4 + t];
    if (c != 0.f) {
      short8v hv = *(const short8v*)(H4 + (size_t)t * N_ * D_ + i);
#pragma unroll
      for (int j = 0; j < 8; j++) acc[j] += c * b2f(hv[j]);
    }
  }
  __hip_bfloat16 o[8];
#pragma unroll
  for (int j = 0; j < 8; j++) o[j] = __float2bfloat16(acc[j]);
  *(short8v*)(nb16 + (size_t)v * D2_ + D_ + k) = *(const short8v*)o;
}

// C[z][M,N] = relu(A[M,K] @ BT[z][N,K]^T (+bias)), bf16 out, batched over
// blockIdx.z. 128x128 tile, BK=64, 4 waves (2x2), 16x16x32 MFMA,
// XOR-swizzled LDS staging, XCD-chunked block swizzle per z-slice.
// Epilogue: wave's 64x64 C-tile staged through LDS (reusing As/Bs, rotation
// swizzle) -> 8 x 16B coalesced stores/thread (kills 64 scalar 2B stores +
// the write-allocate RMW fetch of C).
template <bool BIAS>
__global__ __launch_bounds__(256) void gemm_mfma_kernel(
    const __hip_bfloat16* __restrict__ A, const __hip_bfloat16* __restrict__ BT0,
    const float* __restrict__ bias, __hip_bfloat16* __restrict__ C0,
    int M, int N, int K, size_t strideB, size_t strideC) {
  const __hip_bfloat16* BT = BT0 + (size_t)blockIdx.z * strideB;
  __shared__ char lds[32768];
  char* As = lds;
  char* Bs = lds + 16384;
  int tid = threadIdx.x;
  int lane = tid & 63;
  int wv = tid >> 6;
  int wr = wv >> 1, wc = wv & 1;
  int nwg = gridDim.x * gridDim.y;
  int id = blockIdx.y * gridDim.x + blockIdx.x;
  int s = (id & 7) * (nwg >> 3) + (id >> 3);
  int bx = s % gridDim.x, by = s / gridDim.x;
  int row0 = by * 128, col0 = bx * 128;
  int r_ = tid >> 3;
  int s_ = tid & 7;

  floatx4 acc[4][4];
#pragma unroll
  for (int i = 0; i < 4; i++)
#pragma unroll
    for (int j = 0; j < 4; j++) acc[i][j] = floatx4{0.f, 0.f, 0.f, 0.f};

  for (int k0 = 0; k0 < K; k0 += 64) {
    __syncthreads();
#pragma unroll
    for (int is = 0; is < 4; is++) {
      int r = is * 32 + r_;
      int sp = s_ ^ (r & 7);
      gld16(A  + (size_t)(row0 + r) * K + k0 + sp * 8, As + is * 4096 + tid * 16);
      gld16(BT + (size_t)(col0 + r) * K + k0 + sp * 8, Bs + is * 4096 + tid * 16);
    }
    __syncthreads();
#pragma unroll
    for (int kk = 0; kk < 64; kk += 32) {
      int p = (kk >> 3) + (lane >> 4);
      short8v af[4], bf[4];
#pragma unroll
      for (int m = 0; m < 4; m++) {
        int ra = wr * 64 + m * 16 + (lane & 15);
        af[m] = *(const short8v*)(As + ra * 128 + ((p ^ (ra & 7)) << 4));
        int rb = wc * 64 + m * 16 + (lane & 15);
        bf[m] = *(const short8v*)(Bs + rb * 128 + ((p ^ (rb & 7)) << 4));
      }
#pragma unroll
      for (int m = 0; m < 4; m++)
#pragma unroll
        for (int n = 0; n < 4; n++)
          acc[m][n] = __builtin_amdgcn_mfma_f32_16x16x32_bf16(
              af[m], bf[n], acc[m][n], 0, 0, 0);
    }
  }
  // ---- LDS-staged coalesced epilogue ----
  __syncthreads();                       // all waves done reading As/Bs
  char* cs = lds + wv * 8192;            // [64 r][64 c] bf16, slot rot (s+r)&7
#pragma unroll
  for (int m = 0; m < 4; m++) {
#pragma unroll
    for (int n = 0; n < 4; n++) {
      int c = n * 16 + (lane & 15);
      float bv = BIAS ? bias[col0 + wc * 64 + c] : 0.f;
#pragma unroll
      for (int q = 0; q < 4; q++) {
        int r = m * 16 + (lane >> 4) * 4 + q;
        float v = fmaxf(acc[m][n][q] + bv, 0.f);
        int byte = r * 128 + ((((c >> 3) + r) & 7) << 4) + ((c & 7) << 1);
        *(__hip_bfloat16*)(cs + byte) = __float2bfloat16(v);
      }
    }
  }
  // wave-local LDS dependency; compiler inserts lgkmcnt wait
  __hip_bfloat16* C = C0 + (size_t)blockIdx.z * strideC;
#pragma unroll
  for (int i = 0; i < 8; i++) {
    int r = i * 8 + (lane >> 3);
    int s8 = lane & 7;
    int p = (s8 + r) & 7;
    short8v v = *(const short8v*)(cs + r * 128 + (p << 4));
    int grow = row0 + wr * 64 + r;
    int gcol = col0 + wc * 64 + s8 * 8;
    *(short8v*)(C + (size_t)grow * N + gcol) = v;
  }
}

// row L2-normalize: z bf16 -> out fp32. 192 of 256 threads carry 4 elems.
__global__ __launch_bounds__(256) void norm_kernel(
    const __hip_bfloat16* __restrict__ z, float* __restrict__ out) {
  int v = blockIdx.x, tid = threadIdx.x;
  float e[4] = {0.f, 0.f, 0.f, 0.f};
  if (tid < 192) {
    short4 a = *(const short4*)(z + (size_t)v * D_ + tid * 4);
    e[0] = b2f(a.x); e[1] = b2f(a.y); e[2] = b2f(a.z); e[3] = b2f(a.w);
  }
  float q = e[0] * e[0] + e[1] * e[1] + e[2] * e[2] + e[3] * e[3];
  __shared__ float red[4];
  __shared__ float sc;
  float wq = wave_sum(q);
  int lane = tid & 63, w = tid >> 6;
  if (lane == 0) red[w] = wq;
  __syncthreads();
  if (tid == 0) {
    float S = red[0] + red[1] + red[2] + red[3];
    float norm = sqrtf(S);
    sc = (norm == 0.f) ? 1.f : (1.f / norm);
  }
  __syncthreads();
  if (tid < 192) {
    float s = sc;
    float4 o = {e[0] * s, e[1] * s, e[2] * s, e[3] * s};
    *(float4*)(out + (size_t)v * D_ + tid * 4) = o;
  }
}

extern "C" void kernel_launch(void* const* d_in, const int* in_sizes, int n_in,
                              void* d_out, int out_size, void* d_ws,
                              size_t ws_size, hipStream_t stream) {
  (void)in_sizes; (void)n_in; (void)out_size; (void)ws_size;
  const float* h      = (const float*)d_in[0];
  const float* W_text = (const float*)d_in[1];
  const float* c_text = (const float*)d_in[2];
  const float* W_user = (const float*)d_in[3];
  const float* c_user = (const float*)d_in[4];
  const float* W_dst  = (const float*)d_in[5];
  const float* c_dst  = (const float*)d_in[6];
  const float* gamma  = (const float*)d_in[7];
  const float* beta   = (const float*)d_in[8];
  const float* W_lin  = (const float*)d_in[9];
  const float* b_lin  = (const float*)d_in[10];
  const int* src      = (const int*)d_in[11];
  const int* dst      = (const int*)d_in[12];
  const int* etype    = (const int*)d_in[13];
  const int* hete     = (const int*)d_in[14];
  float* out          = (float*)d_out;

  char* ws = (char*)d_ws;
  __hip_bfloat16* xb   = (__hip_bfloat16*)(ws + OFF_XB);
  __hip_bfloat16* WcT  = (__hip_bfloat16*)(ws + OFF_WCT);
  __hip_bfloat16* WlT  = (__hip_bfloat16*)(ws + OFF_WLT);
  __hip_bfloat16* nb16 = (__hip_bfloat16*)(ws + OFF_NB16);
  __hip_bfloat16* H4   = (__hip_bfloat16*)(ws + OFF_H4);
  __hip_bfloat16* zbuf = (__hip_bfloat16*)(ws + OFF_ZB);
  __hip_bfloat16* n1c  = (__hip_bfloat16*)(ws + OFF_N1C);
  int* target   = (int*)(ws + OFF_TG);
  int* payload  = (int*)(ws + OFF_PAY);
  int* cnt4     = (int*)(ws + OFF_CNT);
  int* base     = (int*)(ws + OFF_BASE);
  int* cursor   = (int*)(ws + OFF_CUR);
  int* blockcnt = (int*)(ws + OFF_BC);
  int* scanout  = (int*)(ws + OFF_SCAN);

  hipMemsetAsync(cnt4, 0, (size_t)N_ * 4 * 4, stream);
  hipMemsetAsync(cursor, 0, (size_t)N_ * 4, stream);

  combine_wt_kernel<<<dim3(144, 12), 256, 0, stream>>>(
      W_text, c_text, W_user, c_user, W_dst, c_dst, WcT);
  wlint_kernel<<<(D2_ * D_) / 256, 256, 0, stream>>>(W_lin, WlT);
  ln_kernel<<<N_, 256, 0, stream>>>(h, gamma, beta, xb);
  edge_a_kernel<<<E_ / 256, 256, 0, stream>>>(hete, dst, etype, blockcnt, cnt4);
  scan_kernel<<<1, 512, 0, stream>>>(blockcnt, scanout);
  edge_b_kernel<<<E_ / 256, 256, 0, stream>>>(hete, dst, scanout, target);
  base_scan_kernel<<<1, 1024, 0, stream>>>(cnt4, base);
  edge_sort_kernel<<<E_ / 256, 256, 0, stream>>>(target, src, etype, hete,
                                                 base, cursor, payload);

  const size_t HSTRIDE = (size_t)N_ * D_;
  const dim3 ggrid(D_ / 128, N_ / 128, 4);

  // dst family: 4 GEMMs batched (z) -> H4, then weighted combine into nb16
  gemm_mfma_kernel<false><<<ggrid, 256, 0, stream>>>(
      xb, WcT + (size_t)8 * DSQ_, nullptr, H4, N_, D_, D_, DSQ_, HSTRIDE);
  combine_n2_kernel<<<(N_ * D_) / (256 * 8), 256, 0, stream>>>(H4, cnt4, nb16);

  // src families: 2 passes of 4 groups each
  gemm_mfma_kernel<false><<<ggrid, 256, 0, stream>>>(
      xb, WcT, nullptr, H4, N_, D_, D_, DSQ_, HSTRIDE);
  gather_n1_kernel<true><<<N_ / 4, 256, 0, stream>>>(H4, base, payload, n1c,
                                                     nb16, 0);
  gemm_mfma_kernel<false><<<ggrid, 256, 0, stream>>>(
      xb, WcT + (size_t)4 * DSQ_, nullptr, H4, N_, D_, D_, DSQ_, HSTRIDE);
  gather_n1_kernel<false><<<N_ / 4, 256, 0, stream>>>(H4, base, payload, n1c,
                                                      nb16, 4);

  // z = relu(nb16 @ W_lin + b_lin) -> zbuf bf16 (reuses H4), then norm
  gemm_mfma_kernel<true><<<dim3(D_ / 128, N_ / 128, 1), 256, 0, stream>>>(
      nb16, WlT, b_lin, zbuf, N_, D_, D2_, 0, 0);
  norm_kernel<<<N_, 256, 0, stream>>>(zbuf, out);
}

// Round 13
// 478.357 us; speedup vs baseline: 1.0486x; 1.0292x over previous
//
#include <hip/hip_runtime.h>
#include <hip/hip_bf16.h>
#include <cstdint>

static constexpr int N_  = 16384;
static constexpr int E_  = 131072;
static constexpr int D_  = 768;
static constexpr int D2_ = 1536;
static constexpr int DSQ_ = D_ * D_;

// ---------------- workspace layout (bytes), total ~219.3 MB ----------------
static constexpr size_t OFF_XB   = 0;            // N*D bf16    = 25165824
static constexpr size_t OFF_WBT  = 25165824;     // 9*D*D bf16  = 10616832
static constexpr size_t OFF_WLT  = 39321600;     // D*2D bf16   = 2359296
static constexpr size_t OFF_NB16 = 41680896;     // N*2D bf16   = 50331648
static constexpr size_t OFF_Y3   = 92012544;     // 3 * N*D bf16 = 75497472
static constexpr size_t OFF_ZB   = 92012544;     // N*D bf16 (reuses Y3 after gathers)
static constexpr size_t OFF_N1C  = 192675840;    // N*D bf16 carry = 25165824
static constexpr size_t OFF_TG   = 217841664;    // E int32     = 524288
static constexpr size_t OFF_PAY  = 218365952;    // E int32     = 524288
static constexpr size_t OFF_CNT  = 218890240;    // N*4 int32   = 262144
static constexpr size_t OFF_BASE = 219152384;    // (N+1) int32, padded to 65552
static constexpr size_t OFF_CUR  = 219217936;    // N int32     = 65536
static constexpr size_t OFF_BC   = 219283472;    // 512 int32
static constexpr size_t OFF_SCAN = 219285520;    // 513 int32

typedef __attribute__((ext_vector_type(8))) short short8v;
typedef __attribute__((ext_vector_type(4))) float floatx4;

__device__ __forceinline__ void gld16(const void* g, void* l) {
  __builtin_amdgcn_global_load_lds(
      (const __attribute__((address_space(1))) unsigned int*)g,
      (__attribute__((address_space(3))) unsigned int*)l, 16, 0, 0);
}

__device__ __forceinline__ float b2f(short u) {
  union { unsigned int i; float f; } x;
  x.i = ((unsigned int)(unsigned short)u) << 16;
  return x.f;
}

__device__ __forceinline__ float wave_sum(float v) {
#pragma unroll
  for (int o = 32; o; o >>= 1) v += __shfl_down(v, o, 64);
  return v;
}

// WbT[fb][h][d] = W_f[b][d][h] (bf16), fb = f*3+b; LDS 64x64 transpose so
// both global reads and writes are coalesced.
__global__ __launch_bounds__(256) void wbasis_t_kernel(
    const float* __restrict__ Wt, const float* __restrict__ Wu,
    const float* __restrict__ Wd, __hip_bfloat16* __restrict__ WbT) {
  __shared__ float tile[64][65];
  int fb = blockIdx.y;                        // 0..8
  int f = fb / 3, b = fb % 3;
  const float* W = ((f == 0) ? Wt : ((f == 1) ? Wu : Wd)) + (size_t)b * DSQ_;
  int dt = (blockIdx.x / 12) * 64;            // d-tile base
  int ht = (blockIdx.x % 12) * 64;            // h-tile base
  int tid = threadIdx.x;
#pragma unroll
  for (int jj = 0; jj < 16; jj++) {
    int idx = jj * 256 + tid;
    int rr = idx >> 6, cc = idx & 63;         // (d-off, h-off)
    tile[rr][cc] = W[(size_t)(dt + rr) * D_ + ht + cc];
  }
  __syncthreads();
#pragma unroll
  for (int jj = 0; jj < 16; jj++) {
    int idx = jj * 256 + tid;
    int hh = idx >> 6, dd = idx & 63;
    WbT[(size_t)fb * DSQ_ + (size_t)(ht + hh) * D_ + dt + dd] =
        __float2bfloat16(tile[dd][hh]);
  }
}

// W_linT[h][k] = W_lin[k][h] (bf16)
__global__ __launch_bounds__(256) void wlint_kernel(
    const float* __restrict__ W, __hip_bfloat16* __restrict__ WT) {
  int i = blockIdx.x * 256 + threadIdx.x;    // < 2D*D, i = k*768 + h
  int k = i / D_, h = i % D_;
  WT[(size_t)h * D2_ + k] = __float2bfloat16(W[i]);
}

__global__ __launch_bounds__(256) void ln_kernel(
    const float* __restrict__ h, const float* __restrict__ gamma,
    const float* __restrict__ beta, __hip_bfloat16* __restrict__ x) {
  int v = blockIdx.x, tid = threadIdx.x;
  const float* hr = h + (size_t)v * D_;
  float e0 = hr[tid], e1 = hr[tid + 256], e2 = hr[tid + 512];
  float s = e0 + e1 + e2;
  float q = e0 * e0 + e1 * e1 + e2 * e2;
  __shared__ float red[8];
  __shared__ float mv[2];
  float ws_ = wave_sum(s), wq = wave_sum(q);
  int lane = tid & 63, w = tid >> 6;
  if (lane == 0) { red[w] = ws_; red[4 + w] = wq; }
  __syncthreads();
  if (tid == 0) {
    float S = red[0] + red[1] + red[2] + red[3];
    float Q = red[4] + red[5] + red[6] + red[7];
    float mu = S * (1.0f / D_);
    float var = Q * (1.0f / D_) - mu * mu;
    mv[0] = mu;
    mv[1] = rsqrtf(var + 1e-5f);
  }
  __syncthreads();
  float mu = mv[0], rstd = mv[1];
  __hip_bfloat16* xr = x + (size_t)v * D_;
  xr[tid]       = __float2bfloat16((e0 - mu) * rstd * gamma[tid]       + beta[tid]);
  xr[tid + 256] = __float2bfloat16((e1 - mu) * rstd * gamma[tid + 256] + beta[tid + 256]);
  xr[tid + 512] = __float2bfloat16((e2 - mu) * rstd * gamma[tid + 512] + beta[tid + 512]);
}

// per-block hete counts + (dst,etype) histogram
__global__ __launch_bounds__(256) void edge_a_kernel(
    const int* __restrict__ hete, const int* __restrict__ dst,
    const int* __restrict__ etype, int* __restrict__ blockcnt,
    int* __restrict__ cnt4) {
  int j = blockIdx.x * 256 + threadIdx.x;
  int flag = hete[j] > 0;
  unsigned long long m = __ballot(flag);
  __shared__ int wsum[4];
  int lane = threadIdx.x & 63, w = threadIdx.x >> 6;
  if (lane == 0) wsum[w] = __popcll(m);
  __syncthreads();
  if (threadIdx.x == 0)
    blockcnt[blockIdx.x] = wsum[0] + wsum[1] + wsum[2] + wsum[3];
  atomicAdd(&cnt4[dst[j] * 4 + etype[j]], 1);
}

// single-block scan over 512 block counts -> exclusive offsets + total K
__global__ __launch_bounds__(512) void scan_kernel(
    const int* __restrict__ blockcnt, int* __restrict__ scanout) {
  __shared__ int s[512];
  int t = threadIdx.x;
  int v = blockcnt[t];
  s[t] = v;
  __syncthreads();
  for (int o = 1; o < 512; o <<= 1) {
    int add = (t >= o) ? s[t - o] : 0;
    __syncthreads();
    s[t] += add;
    __syncthreads();
  }
  scanout[t] = s[t] - v;             // exclusive prefix
  if (t == 511) scanout[512] = s[511];  // total hete count K
}

// target[j] = dst[perm_inv[j]]
__global__ __launch_bounds__(256) void edge_b_kernel(
    const int* __restrict__ hete, const int* __restrict__ dst,
    const int* __restrict__ scanout, int* __restrict__ target) {
  int j = blockIdx.x * 256 + threadIdx.x;
  int flag = hete[j] > 0;
  unsigned long long m = __ballot(flag);
  __shared__ int wsum[4];
  int lane = threadIdx.x & 63, w = threadIdx.x >> 6;
  if (lane == 0) wsum[w] = __popcll(m);
  __syncthreads();
  int wpre = 0;
#pragma unroll
  for (int i = 0; i < 4; i++) wpre += (i < w) ? wsum[i] : 0;
  int lpre = __popcll(m & ((1ull << lane) - 1ull));
  int hcum = scanout[blockIdx.x] + wpre + lpre;  // # hete edges with idx < j
  int K = scanout[512];
  int e = flag ? hcum : (K + j - hcum);
  target[j] = dst[e];
}

// base[v] = exclusive prefix of deg[v] = sum_t cnt4[v,t]; base[N]=E
__global__ __launch_bounds__(1024) void base_scan_kernel(
    const int* __restrict__ cnt4, int* __restrict__ base) {
  __shared__ int s[1024];
  int t = threadIdx.x;
  int loc[16];
  int sum = 0;
#pragma unroll
  for (int i = 0; i < 16; i++) {
    int v = t * 16 + i;
    int d = cnt4[v * 4] + cnt4[v * 4 + 1] + cnt4[v * 4 + 2] + cnt4[v * 4 + 3];
    loc[i] = sum;
    sum += d;
  }
  s[t] = sum;
  __syncthreads();
  for (int o = 1; o < 1024; o <<= 1) {
    int add = (t >= o) ? s[t - o] : 0;
    __syncthreads();
    s[t] += add;
    __syncthreads();
  }
  int pre = t ? s[t - 1] : 0;
#pragma unroll
  for (int i = 0; i < 16; i++) base[t * 16 + i] = pre + loc[i];
  if (t == 1023) base[N_] = s[1023];
}

// payload[base[target[j]] + cursor++] = g<<14 | src[j]
__global__ __launch_bounds__(256) void edge_sort_kernel(
    const int* __restrict__ target, const int* __restrict__ src,
    const int* __restrict__ etype, const int* __restrict__ hete,
    const int* __restrict__ base, int* __restrict__ cursor,
    int* __restrict__ payload) {
  int j = blockIdx.x * 256 + threadIdx.x;
  int v = target[j];
  int p = base[v] + atomicAdd(&cursor[v], 1);
  int g = ((hete[j] > 0) ? 0 : 4) + etype[j];
  payload[p] = (g << 14) | src[j];
}

// one wave per node; edges of types [g0, g0+4). Per edge: combine 3 basis
// rows with coeff[t], relu AFTER the combine, accumulate. Lane owns elems
// [lane*8,+8) and [512+lane*4,+4).
template <bool FIRST>
__global__ __launch_bounds__(256) void gather_n1_kernel(
    const __hip_bfloat16* __restrict__ Y, const float* __restrict__ coeff,
    const int* __restrict__ base, const int* __restrict__ payload,
    __hip_bfloat16* __restrict__ n1c, __hip_bfloat16* __restrict__ nb16,
    int g0) {
  int wv = threadIdx.x >> 6, lane = threadIdx.x & 63;
  int v = blockIdx.x * 4 + wv;
  int b0 = base[v], b1 = base[v + 1];
  float cf[12];
#pragma unroll
  for (int i = 0; i < 12; i++) cf[i] = coeff[i];   // [t][b], t=0..3
  float acc[12];
  if (FIRST) {
#pragma unroll
    for (int i = 0; i < 12; i++) acc[i] = 0.f;
  } else {
    short8v a8 = *(const short8v*)(n1c + (size_t)v * D_ + lane * 8);
    short4  b4 = *(const short4*)(n1c + (size_t)v * D_ + 512 + lane * 4);
#pragma unroll
    for (int i = 0; i < 8; i++) acc[i] = b2f(a8[i]);
    acc[8] = b2f(b4.x); acc[9] = b2f(b4.y);
    acc[10] = b2f(b4.z); acc[11] = b2f(b4.w);
  }
  const size_t YS = (size_t)N_ * D_;
  for (int idx = b0; idx < b1; ++idx) {
    int pl = payload[idx];
    int t = (pl >> 14) - g0;
    if ((unsigned)t > 3u) continue;
    float c0 = cf[t * 3], c1 = cf[t * 3 + 1], c2 = cf[t * 3 + 2];
    const __hip_bfloat16* r0 = Y + (size_t)(pl & 16383) * D_;
    short8v a0 = *(const short8v*)(r0 + lane * 8);
    short8v a1 = *(const short8v*)(r0 + YS + lane * 8);
    short8v a2 = *(const short8v*)(r0 + 2 * YS + lane * 8);
    short4  b0v = *(const short4*)(r0 + 512 + lane * 4);
    short4  b1v = *(const short4*)(r0 + YS + 512 + lane * 4);
    short4  b2v = *(const short4*)(r0 + 2 * YS + 512 + lane * 4);
#pragma unroll
    for (int i = 0; i < 8; i++)
      acc[i] += fmaxf(c0 * b2f(a0[i]) + c1 * b2f(a1[i]) + c2 * b2f(a2[i]), 0.f);
    acc[8]  += fmaxf(c0 * b2f(b0v.x) + c1 * b2f(b1v.x) + c2 * b2f(b2v.x), 0.f);
    acc[9]  += fmaxf(c0 * b2f(b0v.y) + c1 * b2f(b1v.y) + c2 * b2f(b2v.y), 0.f);
    acc[10] += fmaxf(c0 * b2f(b0v.z) + c1 * b2f(b1v.z) + c2 * b2f(b2v.z), 0.f);
    acc[11] += fmaxf(c0 * b2f(b0v.w) + c1 * b2f(b1v.w) + c2 * b2f(b2v.w), 0.f);
  }
  __hip_bfloat16 o[12];
#pragma unroll
  for (int i = 0; i < 12; i++) o[i] = __float2bfloat16(acc[i]);
  if (FIRST) {
    *(short8v*)(n1c + (size_t)v * D_ + lane * 8) = *(const short8v*)o;
    *(short4*)(n1c + (size_t)v * D_ + 512 + lane * 4) = *(const short4*)(o + 8);
  } else {
    *(short8v*)(nb16 + (size_t)v * D2_ + lane * 8) = *(const short8v*)o;
    *(short4*)(nb16 + (size_t)v * D2_ + 512 + lane * 4) = *(const short4*)(o + 8);
  }
}

// nb16[v][768+k] = sum_t cnt4[v,t] * relu(sum_b cd[t,b] * Y[b][v][k])
__global__ __launch_bounds__(256) void combine_n2_kernel(
    const __hip_bfloat16* __restrict__ Y, const float* __restrict__ cd,
    const int* __restrict__ cnt4, __hip_bfloat16* __restrict__ nb16) {
  size_t i = ((size_t)blockIdx.x * 256 + threadIdx.x) * 8;  // < N*D
  int v = (int)(i / D_);
  int k = (int)(i % D_);
  const size_t YS = (size_t)N_ * D_;
  short8v y0 = *(const short8v*)(Y + i);
  short8v y1 = *(const short8v*)(Y + YS + i);
  short8v y2 = *(const short8v*)(Y + 2 * YS + i);
  float f0[8], f1[8], f2[8];
#pragma unroll
  for (int j = 0; j < 8; j++) {
    f0[j] = b2f(y0[j]); f1[j] = b2f(y1[j]); f2[j] = b2f(y2[j]);
  }
  float acc[8] = {0.f, 0.f, 0.f, 0.f, 0.f, 0.f, 0.f, 0.f};
#pragma unroll
  for (int t = 0; t < 4; t++) {
    float c = (float)cnt4[v * 4 + t];
    if (c != 0.f) {
      float d0 = cd[t * 3], d1 = cd[t * 3 + 1], d2 = cd[t * 3 + 2];
#pragma unroll
      for (int j = 0; j < 8; j++)
        acc[j] += c * fmaxf(d0 * f0[j] + d1 * f1[j] + d2 * f2[j], 0.f);
    }
  }
  __hip_bfloat16 o[8];
#pragma unroll
  for (int j = 0; j < 8; j++) o[j] = __float2bfloat16(acc[j]);
  *(short8v*)(nb16 + (size_t)v * D2_ + D_ + k) = *(const short8v*)o;
}

// C[z][M,N] = op(A[M,K] @ BT[z][N,K]^T (+bias)), op = relu iff RELU.
// bf16 out, batched over blockIdx.z with z FOLDED into the XCD swizzle
// ((bx, z, by) ordering) so each XCD's by-chunk of A stays L2-resident
// across all z and bx. 128x128 tile, BK=64, 4 waves (2x2), 16x16x32 MFMA,
// XOR-swizzled LDS. Epilogue: LDS-staged -> 8 x 16B stores/thread.
// NOTE: RELU=false for basis GEMMs (Y must keep negatives; relu happens
// after the coefficient combine in gather/combine kernels) — r12's bug.
template <bool BIAS, bool RELU>
__global__ __launch_bounds__(256) void gemm_mfma_kernel(
    const __hip_bfloat16* __restrict__ A, const __hip_bfloat16* __restrict__ BT0,
    const float* __restrict__ bias, __hip_bfloat16* __restrict__ C0,
    int M, int N, int K, size_t strideB, size_t strideC) {
  __shared__ char lds[32768];
  char* As = lds;
  char* Bs = lds + 16384;
  int tid = threadIdx.x;
  int lane = tid & 63;
  int wv = tid >> 6;
  int wr = wv >> 1, wc = wv & 1;
  int gx = gridDim.x, gz = gridDim.z;
  int nwg = gx * gridDim.y * gz;
  int id = (blockIdx.z * gridDim.y + blockIdx.y) * gx + blockIdx.x;
  int s = (id & 7) * (nwg >> 3) + (id >> 3);
  int bx = s % gx;
  int rem = s / gx;
  int z = rem % gz;
  int by = rem / gz;
  const __hip_bfloat16* BT = BT0 + (size_t)z * strideB;
  int row0 = by * 128, col0 = bx * 128;
  int r_ = tid >> 3;
  int s_ = tid & 7;

  floatx4 acc[4][4];
#pragma unroll
  for (int i = 0; i < 4; i++)
#pragma unroll
    for (int j = 0; j < 4; j++) acc[i][j] = floatx4{0.f, 0.f, 0.f, 0.f};

  for (int k0 = 0; k0 < K; k0 += 64) {
    __syncthreads();
#pragma unroll
    for (int is = 0; is < 4; is++) {
      int r = is * 32 + r_;
      int sp = s_ ^ (r & 7);
      gld16(A  + (size_t)(row0 + r) * K + k0 + sp * 8, As + is * 4096 + tid * 16);
      gld16(BT + (size_t)(col0 + r) * K + k0 + sp * 8, Bs + is * 4096 + tid * 16);
    }
    __syncthreads();
#pragma unroll
    for (int kk = 0; kk < 64; kk += 32) {
      int p = (kk >> 3) + (lane >> 4);
      short8v af[4], bf[4];
#pragma unroll
      for (int m = 0; m < 4; m++) {
        int ra = wr * 64 + m * 16 + (lane & 15);
        af[m] = *(const short8v*)(As + ra * 128 + ((p ^ (ra & 7)) << 4));
        int rb = wc * 64 + m * 16 + (lane & 15);
        bf[m] = *(const short8v*)(Bs + rb * 128 + ((p ^ (rb & 7)) << 4));
      }
#pragma unroll
      for (int m = 0; m < 4; m++)
#pragma unroll
        for (int n = 0; n < 4; n++)
          acc[m][n] = __builtin_amdgcn_mfma_f32_16x16x32_bf16(
              af[m], bf[n], acc[m][n], 0, 0, 0);
    }
  }
  // ---- LDS-staged coalesced epilogue ----
  __syncthreads();                       // all waves done reading As/Bs
  char* cs = lds + wv * 8192;            // [64 r][64 c] bf16, slot rot (s+r)&7
#pragma unroll
  for (int m = 0; m < 4; m++) {
#pragma unroll
    for (int n = 0; n < 4; n++) {
      int c = n * 16 + (lane & 15);
      float bv = BIAS ? bias[col0 + wc * 64 + c] : 0.f;
#pragma unroll
      for (int q = 0; q < 4; q++) {
        int r = m * 16 + (lane >> 4) * 4 + q;
        float v = acc[m][n][q] + bv;
        if (RELU) v = fmaxf(v, 0.f);
        int byte = r * 128 + ((((c >> 3) + r) & 7) << 4) + ((c & 7) << 1);
        *(__hip_bfloat16*)(cs + byte) = __float2bfloat16(v);
      }
    }
  }
  __hip_bfloat16* C = C0 + (size_t)z * strideC;
#pragma unroll
  for (int i = 0; i < 8; i++) {
    int r = i * 8 + (lane >> 3);
    int s8 = lane & 7;
    int p = (s8 + r) & 7;
    short8v v = *(const short8v*)(cs + r * 128 + (p << 4));
    int grow = row0 + wr * 64 + r;
    int gcol = col0 + wc * 64 + s8 * 8;
    *(short8v*)(C + (size_t)grow * N + gcol) = v;
  }
}

// row L2-normalize: z bf16 -> out fp32. 192 of 256 threads carry 4 elems.
__global__ __launch_bounds__(256) void norm_kernel(
    const __hip_bfloat16* __restrict__ z, float* __restrict__ out) {
  int v = blockIdx.x, tid = threadIdx.x;
  float e[4] = {0.f, 0.f, 0.f, 0.f};
  if (tid < 192) {
    short4 a = *(const short4*)(z + (size_t)v * D_ + tid * 4);
    e[0] = b2f(a.x); e[1] = b2f(a.y); e[2] = b2f(a.z); e[3] = b2f(a.w);
  }
  float q = e[0] * e[0] + e[1] * e[1] + e[2] * e[2] + e[3] * e[3];
  __shared__ float red[4];
  __shared__ float sc;
  float wq = wave_sum(q);
  int lane = tid & 63, w = tid >> 6;
  if (lane == 0) red[w] = wq;
  __syncthreads();
  if (tid == 0) {
    float S = red[0] + red[1] + red[2] + red[3];
    float norm = sqrtf(S);
    sc = (norm == 0.f) ? 1.f : (1.f / norm);
  }
  __syncthreads();
  if (tid < 192) {
    float s = sc;
    float4 o = {e[0] * s, e[1] * s, e[2] * s, e[3] * s};
    *(float4*)(out + (size_t)v * D_ + tid * 4) = o;
  }
}

extern "C" void kernel_launch(void* const* d_in, const int* in_sizes, int n_in,
                              void* d_out, int out_size, void* d_ws,
                              size_t ws_size, hipStream_t stream) {
  (void)in_sizes; (void)n_in; (void)out_size; (void)ws_size;
  const float* h      = (const float*)d_in[0];
  const float* W_text = (const float*)d_in[1];
  const float* c_text = (const float*)d_in[2];
  const float* W_user = (const float*)d_in[3];
  const float* c_user = (const float*)d_in[4];
  const float* W_dst  = (const float*)d_in[5];
  const float* c_dst  = (const float*)d_in[6];
  const float* gamma  = (const float*)d_in[7];
  const float* beta   = (const float*)d_in[8];
  const float* W_lin  = (const float*)d_in[9];
  const float* b_lin  = (const float*)d_in[10];
  const int* src      = (const int*)d_in[11];
  const int* dst      = (const int*)d_in[12];
  const int* etype    = (const int*)d_in[13];
  const int* hete     = (const int*)d_in[14];
  float* out          = (float*)d_out;

  char* ws = (char*)d_ws;
  __hip_bfloat16* xb   = (__hip_bfloat16*)(ws + OFF_XB);
  __hip_bfloat16* WbT  = (__hip_bfloat16*)(ws + OFF_WBT);
  __hip_bfloat16* WlT  = (__hip_bfloat16*)(ws + OFF_WLT);
  __hip_bfloat16* nb16 = (__hip_bfloat16*)(ws + OFF_NB16);
  __hip_bfloat16* Y3   = (__hip_bfloat16*)(ws + OFF_Y3);
  __hip_bfloat16* zbuf = (__hip_bfloat16*)(ws + OFF_ZB);
  __hip_bfloat16* n1c  = (__hip_bfloat16*)(ws + OFF_N1C);
  int* target   = (int*)(ws + OFF_TG);
  int* payload  = (int*)(ws + OFF_PAY);
  int* cnt4     = (int*)(ws + OFF_CNT);
  int* base     = (int*)(ws + OFF_BASE);
  int* cursor   = (int*)(ws + OFF_CUR);
  int* blockcnt = (int*)(ws + OFF_BC);
  int* scanout  = (int*)(ws + OFF_SCAN);

  hipMemsetAsync(cnt4, 0, (size_t)N_ * 4 * 4, stream);
  hipMemsetAsync(cursor, 0, (size_t)N_ * 4, stream);

  wbasis_t_kernel<<<dim3(144, 9), 256, 0, stream>>>(W_text, W_user, W_dst, WbT);
  wlint_kernel<<<(D2_ * D_) / 256, 256, 0, stream>>>(W_lin, WlT);
  ln_kernel<<<N_, 256, 0, stream>>>(h, gamma, beta, xb);
  edge_a_kernel<<<E_ / 256, 256, 0, stream>>>(hete, dst, etype, blockcnt, cnt4);
  scan_kernel<<<1, 512, 0, stream>>>(blockcnt, scanout);
  edge_b_kernel<<<E_ / 256, 256, 0, stream>>>(hete, dst, scanout, target);
  base_scan_kernel<<<1, 1024, 0, stream>>>(cnt4, base);
  edge_sort_kernel<<<E_ / 256, 256, 0, stream>>>(target, src, etype, hete,
                                                 base, cursor, payload);

  const size_t HSTRIDE = (size_t)N_ * D_;
  const dim3 ggrid(D_ / 128, N_ / 128, 3);

  // dst family: 3 basis GEMMs (NO relu) -> Y3, then coeff+relu+count combine
  gemm_mfma_kernel<false, false><<<ggrid, 256, 0, stream>>>(
      xb, WbT + (size_t)6 * DSQ_, nullptr, Y3, N_, D_, D_, DSQ_, HSTRIDE);
  combine_n2_kernel<<<(N_ * D_) / (256 * 8), 256, 0, stream>>>(Y3, c_dst,
                                                               cnt4, nb16);
  // text family (hete edges, g in [0,4))
  gemm_mfma_kernel<false, false><<<ggrid, 256, 0, stream>>>(
      xb, WbT, nullptr, Y3, N_, D_, D_, DSQ_, HSTRIDE);
  gather_n1_kernel<true><<<N_ / 4, 256, 0, stream>>>(Y3, c_text, base, payload,
                                                     n1c, nb16, 0);
  // user family (homo edges, g in [4,8))
  gemm_mfma_kernel<false, false><<<ggrid, 256, 0, stream>>>(
      xb, WbT + (size_t)3 * DSQ_, nullptr, Y3, N_, D_, D_, DSQ_, HSTRIDE);
  gather_n1_kernel<false><<<N_ / 4, 256, 0, stream>>>(Y3, c_user, base,
                                                      payload, n1c, nb16, 4);

  // z = relu(nb16 @ W_lin + b_lin) -> zbuf bf16 (reuses Y3), then norm
  gemm_mfma_kernel<true, true><<<dim3(D_ / 128, N_ / 128, 1), 256, 0, stream>>>(
      nb16, WlT, b_lin, zbuf, N_, D_, D2_, 0, 0);
  norm_kernel<<<N_, 256, 0, stream>>>(zbuf, out);
}

// Round 14
// 470.294 us; speedup vs baseline: 1.0666x; 1.0171x over previous
//
#include <hip/hip_runtime.h>
#include <hip/hip_bf16.h>
#include <cstdint>

static constexpr int N_  = 16384;
static constexpr int E_  = 131072;
static constexpr int D_  = 768;
static constexpr int D2_ = 1536;
static constexpr int DSQ_ = D_ * D_;

// ---------------- workspace layout (bytes), total ~218.8 MB ----------------
static constexpr size_t OFF_XB   = 0;            // N*D bf16    = 25165824
static constexpr size_t OFF_WBT  = 25165824;     // 9*D*D bf16  = 10616832
static constexpr size_t OFF_WLT  = 39321600;     // D*2D bf16   = 2359296
static constexpr size_t OFF_NB16 = 41680896;     // N*2D bf16   = 50331648
static constexpr size_t OFF_Y3   = 92012544;     // 3 * N*D bf16 = 75497472
static constexpr size_t OFF_ZB   = 92012544;     // N*D bf16 (reuses Y3 after gathers)
static constexpr size_t OFF_N1C  = 192675840;    // N*D bf16 carry = 25165824
static constexpr size_t OFF_PAY  = 217841664;    // E int32     = 524288
static constexpr size_t OFF_CNT  = 218365952;    // N*4 int32   = 262144  } one
static constexpr size_t OFF_CURH = 218628096;    // N int32     = 65536   } memset
static constexpr size_t OFF_CURU = 218693632;    // N int32     = 65536   } span
static constexpr size_t OFF_BASE = 218759168;    // (N+1) int32, padded to 65568
static constexpr size_t OFF_BC   = 218824736;    // 512 int32
static constexpr size_t OFF_SCAN = 218826784;    // 513 int32

typedef __attribute__((ext_vector_type(8))) short short8v;
typedef __attribute__((ext_vector_type(4))) float floatx4;

__device__ __forceinline__ void gld16(const void* g, void* l) {
  __builtin_amdgcn_global_load_lds(
      (const __attribute__((address_space(1))) unsigned int*)g,
      (__attribute__((address_space(3))) unsigned int*)l, 16, 0, 0);
}

__device__ __forceinline__ float b2f(short u) {
  union { unsigned int i; float f; } x;
  x.i = ((unsigned int)(unsigned short)u) << 16;
  return x.f;
}

__device__ __forceinline__ float wave_sum(float v) {
#pragma unroll
  for (int o = 32; o; o >>= 1) v += __shfl_down(v, o, 64);
  return v;
}

// WbT[fb][h][d] = W_f[b][d][h] (bf16), fb = f*3+b; LDS 64x64 transpose so
// both global reads and writes are coalesced.
__global__ __launch_bounds__(256) void wbasis_t_kernel(
    const float* __restrict__ Wt, const float* __restrict__ Wu,
    const float* __restrict__ Wd, __hip_bfloat16* __restrict__ WbT) {
  __shared__ float tile[64][65];
  int fb = blockIdx.y;                        // 0..8
  int f = fb / 3, b = fb % 3;
  const float* W = ((f == 0) ? Wt : ((f == 1) ? Wu : Wd)) + (size_t)b * DSQ_;
  int dt = (blockIdx.x / 12) * 64;            // d-tile base
  int ht = (blockIdx.x % 12) * 64;            // h-tile base
  int tid = threadIdx.x;
#pragma unroll
  for (int jj = 0; jj < 16; jj++) {
    int idx = jj * 256 + tid;
    int rr = idx >> 6, cc = idx & 63;         // (d-off, h-off)
    tile[rr][cc] = W[(size_t)(dt + rr) * D_ + ht + cc];
  }
  __syncthreads();
#pragma unroll
  for (int jj = 0; jj < 16; jj++) {
    int idx = jj * 256 + tid;
    int hh = idx >> 6, dd = idx & 63;
    WbT[(size_t)fb * DSQ_ + (size_t)(ht + hh) * D_ + dt + dd] =
        __float2bfloat16(tile[dd][hh]);
  }
}

// W_linT[h][k] = W_lin[k][h] (bf16)
__global__ __launch_bounds__(256) void wlint_kernel(
    const float* __restrict__ W, __hip_bfloat16* __restrict__ WT) {
  int i = blockIdx.x * 256 + threadIdx.x;    // < 2D*D, i = k*768 + h
  int k = i / D_, h = i % D_;
  WT[(size_t)h * D2_ + k] = __float2bfloat16(W[i]);
}

__global__ __launch_bounds__(256) void ln_kernel(
    const float* __restrict__ h, const float* __restrict__ gamma,
    const float* __restrict__ beta, __hip_bfloat16* __restrict__ x) {
  int v = blockIdx.x, tid = threadIdx.x;
  const float* hr = h + (size_t)v * D_;
  float e0 = hr[tid], e1 = hr[tid + 256], e2 = hr[tid + 512];
  float s = e0 + e1 + e2;
  float q = e0 * e0 + e1 * e1 + e2 * e2;
  __shared__ float red[8];
  __shared__ float mv[2];
  float ws_ = wave_sum(s), wq = wave_sum(q);
  int lane = tid & 63, w = tid >> 6;
  if (lane == 0) { red[w] = ws_; red[4 + w] = wq; }
  __syncthreads();
  if (tid == 0) {
    float S = red[0] + red[1] + red[2] + red[3];
    float Q = red[4] + red[5] + red[6] + red[7];
    float mu = S * (1.0f / D_);
    float var = Q * (1.0f / D_) - mu * mu;
    mv[0] = mu;
    mv[1] = rsqrtf(var + 1e-5f);
  }
  __syncthreads();
  float mu = mv[0], rstd = mv[1];
  __hip_bfloat16* xr = x + (size_t)v * D_;
  xr[tid]       = __float2bfloat16((e0 - mu) * rstd * gamma[tid]       + beta[tid]);
  xr[tid + 256] = __float2bfloat16((e1 - mu) * rstd * gamma[tid + 256] + beta[tid + 256]);
  xr[tid + 512] = __float2bfloat16((e2 - mu) * rstd * gamma[tid + 512] + beta[tid + 512]);
}

// per-block hete counts + (dst,etype) histogram
__global__ __launch_bounds__(256) void edge_a_kernel(
    const int* __restrict__ hete, const int* __restrict__ dst,
    const int* __restrict__ etype, int* __restrict__ blockcnt,
    int* __restrict__ cnt4) {
  int j = blockIdx.x * 256 + threadIdx.x;
  int flag = hete[j] > 0;
  unsigned long long m = __ballot(flag);
  __shared__ int wsum[4];
  int lane = threadIdx.x & 63, w = threadIdx.x >> 6;
  if (lane == 0) wsum[w] = __popcll(m);
  __syncthreads();
  if (threadIdx.x == 0)
    blockcnt[blockIdx.x] = wsum[0] + wsum[1] + wsum[2] + wsum[3];
  atomicAdd(&cnt4[dst[j] * 4 + etype[j]], 1);
}

// block 0: exclusive scan over 512 blockcnt (+ total K at [512]).
// block 1: base[v] = exclusive prefix of deg[v]; base[N] = E.
__global__ __launch_bounds__(1024) void fused_scan_kernel(
    const int* __restrict__ blockcnt, int* __restrict__ scanout,
    const int* __restrict__ cnt4, int* __restrict__ base) {
  int t = threadIdx.x;
  if (blockIdx.x == 0) {
    __shared__ int s[1024];
    int v = (t < 512) ? blockcnt[t] : 0;
    s[t] = v;
    __syncthreads();
    for (int o = 1; o < 512; o <<= 1) {
      int add = (t >= o) ? s[t - o] : 0;
      __syncthreads();
      s[t] += add;
      __syncthreads();
    }
    if (t < 512) scanout[t] = s[t] - v;
    if (t == 511) scanout[512] = s[511];
  } else {
    __shared__ int s[1024];
    int loc[16];
    int sum = 0;
#pragma unroll
    for (int i = 0; i < 16; i++) {
      int v = t * 16 + i;
      int d = cnt4[v * 4] + cnt4[v * 4 + 1] + cnt4[v * 4 + 2] + cnt4[v * 4 + 3];
      loc[i] = sum;
      sum += d;
    }
    s[t] = sum;
    __syncthreads();
    for (int o = 1; o < 1024; o <<= 1) {
      int add = (t >= o) ? s[t - o] : 0;
      __syncthreads();
      s[t] += add;
      __syncthreads();
    }
    int pre = t ? s[t - 1] : 0;
#pragma unroll
    for (int i = 0; i < 16; i++) base[t * 16 + i] = pre + loc[i];
    if (t == 1023) base[N_] = s[1023];
  }
}

// Fused edge_b + edge_sort with two-ended bucket fill:
// e = perm_inv[j]; v = dst[e]. Hete edges fill [base[v], ...) ascending,
// homo fill (..., base[v+1]-1] descending -> bucket is family-segmented:
// text = [base[v], base[v]+curH[v]), user = [base[v]+curH[v], base[v+1]).
// payload = etype<<14 | src.
__global__ __launch_bounds__(256) void edge_bsort_kernel(
    const int* __restrict__ hete, const int* __restrict__ dst,
    const int* __restrict__ src, const int* __restrict__ etype,
    const int* __restrict__ scanout, const int* __restrict__ base,
    int* __restrict__ curH, int* __restrict__ curU,
    int* __restrict__ payload) {
  int j = blockIdx.x * 256 + threadIdx.x;
  int flag = hete[j] > 0;
  unsigned long long m = __ballot(flag);
  __shared__ int wsum[4];
  int lane = threadIdx.x & 63, w = threadIdx.x >> 6;
  if (lane == 0) wsum[w] = __popcll(m);
  __syncthreads();
  int wpre = 0;
#pragma unroll
  for (int i = 0; i < 4; i++) wpre += (i < w) ? wsum[i] : 0;
  int lpre = __popcll(m & ((1ull << lane) - 1ull));
  int hcum = scanout[blockIdx.x] + wpre + lpre;  // # hete edges with idx < j
  int K = scanout[512];
  int e = flag ? hcum : (K + j - hcum);          // e = perm_inv[j]
  int v = dst[e];
  int p;
  if (flag) p = base[v] + atomicAdd(&curH[v], 1);
  else      p = base[v + 1] - 1 - atomicAdd(&curU[v], 1);
  payload[p] = (etype[j] << 14) | src[j];
}

// one wave per node; iterates ONLY its family segment (no branch). Per edge:
// combine 3 basis rows with coeff[t], relu AFTER the combine, accumulate.
// Lane owns elems [lane*8,+8) and [512+lane*4,+4).
// SEG=0: text = [base[v], base[v]+hcnt[v]); SEG=1: user = [.., base[v+1]).
template <bool FIRST, int SEG>
__global__ __launch_bounds__(256) void gather_n1_kernel(
    const __hip_bfloat16* __restrict__ Y, const float* __restrict__ coeff,
    const int* __restrict__ base, const int* __restrict__ hcnt,
    const int* __restrict__ payload, __hip_bfloat16* __restrict__ n1c,
    __hip_bfloat16* __restrict__ nb16) {
  int wv = threadIdx.x >> 6, lane = threadIdx.x & 63;
  int v = blockIdx.x * 4 + wv;
  int bh = base[v] + hcnt[v];
  int lo = (SEG == 0) ? base[v] : bh;
  int hi = (SEG == 0) ? bh : base[v + 1];
  float cf[12];
#pragma unroll
  for (int i = 0; i < 12; i++) cf[i] = coeff[i];   // [t][b], t=0..3
  float acc[12];
  if (FIRST) {
#pragma unroll
    for (int i = 0; i < 12; i++) acc[i] = 0.f;
  } else {
    short8v a8 = *(const short8v*)(n1c + (size_t)v * D_ + lane * 8);
    short4  b4 = *(const short4*)(n1c + (size_t)v * D_ + 512 + lane * 4);
#pragma unroll
    for (int i = 0; i < 8; i++) acc[i] = b2f(a8[i]);
    acc[8] = b2f(b4.x); acc[9] = b2f(b4.y);
    acc[10] = b2f(b4.z); acc[11] = b2f(b4.w);
  }
  const size_t YS = (size_t)N_ * D_;
  for (int idx = lo; idx < hi; ++idx) {
    int pl = payload[idx];
    int t = pl >> 14;
    float c0 = cf[t * 3], c1 = cf[t * 3 + 1], c2 = cf[t * 3 + 2];
    const __hip_bfloat16* r0 = Y + (size_t)(pl & 16383) * D_;
    short8v a0 = *(const short8v*)(r0 + lane * 8);
    short8v a1 = *(const short8v*)(r0 + YS + lane * 8);
    short8v a2 = *(const short8v*)(r0 + 2 * YS + lane * 8);
    short4  b0v = *(const short4*)(r0 + 512 + lane * 4);
    short4  b1v = *(const short4*)(r0 + YS + 512 + lane * 4);
    short4  b2v = *(const short4*)(r0 + 2 * YS + 512 + lane * 4);
#pragma unroll
    for (int i = 0; i < 8; i++)
      acc[i] += fmaxf(c0 * b2f(a0[i]) + c1 * b2f(a1[i]) + c2 * b2f(a2[i]), 0.f);
    acc[8]  += fmaxf(c0 * b2f(b0v.x) + c1 * b2f(b1v.x) + c2 * b2f(b2v.x), 0.f);
    acc[9]  += fmaxf(c0 * b2f(b0v.y) + c1 * b2f(b1v.y) + c2 * b2f(b2v.y), 0.f);
    acc[10] += fmaxf(c0 * b2f(b0v.z) + c1 * b2f(b1v.z) + c2 * b2f(b2v.z), 0.f);
    acc[11] += fmaxf(c0 * b2f(b0v.w) + c1 * b2f(b1v.w) + c2 * b2f(b2v.w), 0.f);
  }
  __hip_bfloat16 o[12];
#pragma unroll
  for (int i = 0; i < 12; i++) o[i] = __float2bfloat16(acc[i]);
  if (FIRST) {
    *(short8v*)(n1c + (size_t)v * D_ + lane * 8) = *(const short8v*)o;
    *(short4*)(n1c + (size_t)v * D_ + 512 + lane * 4) = *(const short4*)(o + 8);
  } else {
    *(short8v*)(nb16 + (size_t)v * D2_ + lane * 8) = *(const short8v*)o;
    *(short4*)(nb16 + (size_t)v * D2_ + 512 + lane * 4) = *(const short4*)(o + 8);
  }
}

// nb16[v][768+k] = sum_t cnt4[v,t] * relu(sum_b cd[t,b] * Y[b][v][k])
__global__ __launch_bounds__(256) void combine_n2_kernel(
    const __hip_bfloat16* __restrict__ Y, const float* __restrict__ cd,
    const int* __restrict__ cnt4, __hip_bfloat16* __restrict__ nb16) {
  size_t i = ((size_t)blockIdx.x * 256 + threadIdx.x) * 8;  // < N*D
  int v = (int)(i / D_);
  int k = (int)(i % D_);
  const size_t YS = (size_t)N_ * D_;
  short8v y0 = *(const short8v*)(Y + i);
  short8v y1 = *(const short8v*)(Y + YS + i);
  short8v y2 = *(const short8v*)(Y + 2 * YS + i);
  float f0[8], f1[8], f2[8];
#pragma unroll
  for (int j = 0; j < 8; j++) {
    f0[j] = b2f(y0[j]); f1[j] = b2f(y1[j]); f2[j] = b2f(y2[j]);
  }
  float acc[8] = {0.f, 0.f, 0.f, 0.f, 0.f, 0.f, 0.f, 0.f};
#pragma unroll
  for (int t = 0; t < 4; t++) {
    float c = (float)cnt4[v * 4 + t];
    if (c != 0.f) {
      float d0 = cd[t * 3], d1 = cd[t * 3 + 1], d2 = cd[t * 3 + 2];
#pragma unroll
      for (int j = 0; j < 8; j++)
        acc[j] += c * fmaxf(d0 * f0[j] + d1 * f1[j] + d2 * f2[j], 0.f);
    }
  }
  __hip_bfloat16 o[8];
#pragma unroll
  for (int j = 0; j < 8; j++) o[j] = __float2bfloat16(acc[j]);
  *(short8v*)(nb16 + (size_t)v * D2_ + D_ + k) = *(const short8v*)o;
}

// C[z][M,N] = op(A[M,K] @ BT[z][N,K]^T (+bias)), op = relu iff RELU.
// bf16 out, batched over blockIdx.z with z FOLDED into the XCD swizzle
// ((bx, z, by) ordering). 128x128 tile, BK=64, 4 waves (2x2), 16x16x32 MFMA,
// XOR-swizzled LDS. Epilogue: LDS-staged -> 8 x 16B stores/thread.
template <bool BIAS, bool RELU>
__global__ __launch_bounds__(256) void gemm_mfma_kernel(
    const __hip_bfloat16* __restrict__ A, const __hip_bfloat16* __restrict__ BT0,
    const float* __restrict__ bias, __hip_bfloat16* __restrict__ C0,
    int M, int N, int K, size_t strideB, size_t strideC) {
  __shared__ char lds[32768];
  char* As = lds;
  char* Bs = lds + 16384;
  int tid = threadIdx.x;
  int lane = tid & 63;
  int wv = tid >> 6;
  int wr = wv >> 1, wc = wv & 1;
  int gx = gridDim.x, gz = gridDim.z;
  int nwg = gx * gridDim.y * gz;
  int id = (blockIdx.z * gridDim.y + blockIdx.y) * gx + blockIdx.x;
  int s = (id & 7) * (nwg >> 3) + (id >> 3);
  int bx = s % gx;
  int rem = s / gx;
  int z = rem % gz;
  int by = rem / gz;
  const __hip_bfloat16* BT = BT0 + (size_t)z * strideB;
  int row0 = by * 128, col0 = bx * 128;
  int r_ = tid >> 3;
  int s_ = tid & 7;

  floatx4 acc[4][4];
#pragma unroll
  for (int i = 0; i < 4; i++)
#pragma unroll
    for (int j = 0; j < 4; j++) acc[i][j] = floatx4{0.f, 0.f, 0.f, 0.f};

  for (int k0 = 0; k0 < K; k0 += 64) {
    __syncthreads();
#pragma unroll
    for (int is = 0; is < 4; is++) {
      int r = is * 32 + r_;
      int sp = s_ ^ (r & 7);
      gld16(A  + (size_t)(row0 + r) * K + k0 + sp * 8, As + is * 4096 + tid * 16);
      gld16(BT + (size_t)(col0 + r) * K + k0 + sp * 8, Bs + is * 4096 + tid * 16);
    }
    __syncthreads();
#pragma unroll
    for (int kk = 0; kk < 64; kk += 32) {
      int p = (kk >> 3) + (lane >> 4);
      short8v af[4], bf[4];
#pragma unroll
      for (int m = 0; m < 4; m++) {
        int ra = wr * 64 + m * 16 + (lane & 15);
        af[m] = *(const short8v*)(As + ra * 128 + ((p ^ (ra & 7)) << 4));
        int rb = wc * 64 + m * 16 + (lane & 15);
        bf[m] = *(const short8v*)(Bs + rb * 128 + ((p ^ (rb & 7)) << 4));
      }
#pragma unroll
      for (int m = 0; m < 4; m++)
#pragma unroll
        for (int n = 0; n < 4; n++)
          acc[m][n] = __builtin_amdgcn_mfma_f32_16x16x32_bf16(
              af[m], bf[n], acc[m][n], 0, 0, 0);
    }
  }
  // ---- LDS-staged coalesced epilogue ----
  __syncthreads();                       // all waves done reading As/Bs
  char* cs = lds + wv * 8192;            // [64 r][64 c] bf16, slot rot (s+r)&7
#pragma unroll
  for (int m = 0; m < 4; m++) {
#pragma unroll
    for (int n = 0; n < 4; n++) {
      int c = n * 16 + (lane & 15);
      float bv = BIAS ? bias[col0 + wc * 64 + c] : 0.f;
#pragma unroll
      for (int q = 0; q < 4; q++) {
        int r = m * 16 + (lane >> 4) * 4 + q;
        float v = acc[m][n][q] + bv;
        if (RELU) v = fmaxf(v, 0.f);
        int byte = r * 128 + ((((c >> 3) + r) & 7) << 4) + ((c & 7) << 1);
        *(__hip_bfloat16*)(cs + byte) = __float2bfloat16(v);
      }
    }
  }
  __hip_bfloat16* C = C0 + (size_t)z * strideC;
#pragma unroll
  for (int i = 0; i < 8; i++) {
    int r = i * 8 + (lane >> 3);
    int s8 = lane & 7;
    int p = (s8 + r) & 7;
    short8v v = *(const short8v*)(cs + r * 128 + (p << 4));
    int grow = row0 + wr * 64 + r;
    int gcol = col0 + wc * 64 + s8 * 8;
    *(short8v*)(C + (size_t)grow * N + gcol) = v;
  }
}

// row L2-normalize: z bf16 -> out fp32. 192 of 256 threads carry 4 elems.
__global__ __launch_bounds__(256) void norm_kernel(
    const __hip_bfloat16* __restrict__ z, float* __restrict__ out) {
  int v = blockIdx.x, tid = threadIdx.x;
  float e[4] = {0.f, 0.f, 0.f, 0.f};
  if (tid < 192) {
    short4 a = *(const short4*)(z + (size_t)v * D_ + tid * 4);
    e[0] = b2f(a.x); e[1] = b2f(a.y); e[2] = b2f(a.z); e[3] = b2f(a.w);
  }
  float q = e[0] * e[0] + e[1] * e[1] + e[2] * e[2] + e[3] * e[3];
  __shared__ float red[4];
  __shared__ float sc;
  float wq = wave_sum(q);
  int lane = tid & 63, w = tid >> 6;
  if (lane == 0) red[w] = wq;
  __syncthreads();
  if (tid == 0) {
    float S = red[0] + red[1] + red[2] + red[3];
    float norm = sqrtf(S);
    sc = (norm == 0.f) ? 1.f : (1.f / norm);
  }
  __syncthreads();
  if (tid < 192) {
    float s = sc;
    float4 o = {e[0] * s, e[1] * s, e[2] * s, e[3] * s};
    *(float4*)(out + (size_t)v * D_ + tid * 4) = o;
  }
}

extern "C" void kernel_launch(void* const* d_in, const int* in_sizes, int n_in,
                              void* d_out, int out_size, void* d_ws,
                              size_t ws_size, hipStream_t stream) {
  (void)in_sizes; (void)n_in; (void)out_size; (void)ws_size;
  const float* h      = (const float*)d_in[0];
  const float* W_text = (const float*)d_in[1];
  const float* c_text = (const float*)d_in[2];
  const float* W_user = (const float*)d_in[3];
  const float* c_user = (const float*)d_in[4];
  const float* W_dst  = (const float*)d_in[5];
  const float* c_dst  = (const float*)d_in[6];
  const float* gamma  = (const float*)d_in[7];
  const float* beta   = (const float*)d_in[8];
  const float* W_lin  = (const float*)d_in[9];
  const float* b_lin  = (const float*)d_in[10];
  const int* src      = (const int*)d_in[11];
  const int* dst      = (const int*)d_in[12];
  const int* etype    = (const int*)d_in[13];
  const int* hete     = (const int*)d_in[14];
  float* out          = (float*)d_out;

  char* ws = (char*)d_ws;
  __hip_bfloat16* xb   = (__hip_bfloat16*)(ws + OFF_XB);
  __hip_bfloat16* WbT  = (__hip_bfloat16*)(ws + OFF_WBT);
  __hip_bfloat16* WlT  = (__hip_bfloat16*)(ws + OFF_WLT);
  __hip_bfloat16* nb16 = (__hip_bfloat16*)(ws + OFF_NB16);
  __hip_bfloat16* Y3   = (__hip_bfloat16*)(ws + OFF_Y3);
  __hip_bfloat16* zbuf = (__hip_bfloat16*)(ws + OFF_ZB);
  __hip_bfloat16* n1c  = (__hip_bfloat16*)(ws + OFF_N1C);
  int* payload  = (int*)(ws + OFF_PAY);
  int* cnt4     = (int*)(ws + OFF_CNT);
  int* curH     = (int*)(ws + OFF_CURH);
  int* curU     = (int*)(ws + OFF_CURU);
  int* base     = (int*)(ws + OFF_BASE);
  int* blockcnt = (int*)(ws + OFF_BC);
  int* scanout  = (int*)(ws + OFF_SCAN);

  // one memset spans cnt4 + curH + curU (contiguous)
  hipMemsetAsync(cnt4, 0, 262144 + 65536 + 65536, stream);

  wbasis_t_kernel<<<dim3(144, 9), 256, 0, stream>>>(W_text, W_user, W_dst, WbT);
  wlint_kernel<<<(D2_ * D_) / 256, 256, 0, stream>>>(W_lin, WlT);
  ln_kernel<<<N_, 256, 0, stream>>>(h, gamma, beta, xb);
  edge_a_kernel<<<E_ / 256, 256, 0, stream>>>(hete, dst, etype, blockcnt, cnt4);
  fused_scan_kernel<<<2, 1024, 0, stream>>>(blockcnt, scanout, cnt4, base);
  edge_bsort_kernel<<<E_ / 256, 256, 0, stream>>>(hete, dst, src, etype,
                                                  scanout, base, curH, curU,
                                                  payload);

  const size_t HSTRIDE = (size_t)N_ * D_;
  const dim3 ggrid(D_ / 128, N_ / 128, 3);

  // dst family: 3 basis GEMMs (NO relu) -> Y3, then coeff+relu+count combine
  gemm_mfma_kernel<false, false><<<ggrid, 256, 0, stream>>>(
      xb, WbT + (size_t)6 * DSQ_, nullptr, Y3, N_, D_, D_, DSQ_, HSTRIDE);
  combine_n2_kernel<<<(N_ * D_) / (256 * 8), 256, 0, stream>>>(Y3, c_dst,
                                                               cnt4, nb16);
  // text family (hete edges, segment 0)
  gemm_mfma_kernel<false, false><<<ggrid, 256, 0, stream>>>(
      xb, WbT, nullptr, Y3, N_, D_, D_, DSQ_, HSTRIDE);
  gather_n1_kernel<true, 0><<<N_ / 4, 256, 0, stream>>>(
      Y3, c_text, base, curH, payload, n1c, nb16);
  // user family (homo edges, segment 1)
  gemm_mfma_kernel<false, false><<<ggrid, 256, 0, stream>>>(
      xb, WbT + (size_t)3 * DSQ_, nullptr, Y3, N_, D_, D_, DSQ_, HSTRIDE);
  gather_n1_kernel<false, 1><<<N_ / 4, 256, 0, stream>>>(
      Y3, c_user, base, curH, payload, n1c, nb16);

  // z = relu(nb16 @ W_lin + b_lin) -> zbuf bf16 (reuses Y3), then norm
  gemm_mfma_kernel<true, true><<<dim3(D_ / 128, N_ / 128, 1), 256, 0, stream>>>(
      nb16, WlT, b_lin, zbuf, N_, D_, D2_, 0, 0);
  norm_kernel<<<N_, 256, 0, stream>>>(zbuf, out);
}